// Round 13
// baseline (907.771 us; speedup 1.0000x reference)
//
#include <hip/hip_runtime.h>
#include <hip/hip_bf16.h>

#define Bq 64
#define Lq 256
#define Dq 350
#define HDq 128
#define Hq 256
#define G4 512   // 4*HD

typedef unsigned short u16;
typedef unsigned int u32;
typedef __attribute__((ext_vector_type(8))) short bf16x8;
typedef __attribute__((ext_vector_type(4))) float f32x4;

__device__ __forceinline__ float bf2f(u16 u) {
    return __uint_as_float(((u32)u) << 16);
}
__device__ __forceinline__ u16 f2bf(float f) {
    __hip_bfloat16 h = __float2bfloat16(f);
    return *(u16*)&h;
}
__device__ __forceinline__ float bflo(u32 u) {
    return __uint_as_float(u << 16);
}
__device__ __forceinline__ float bfhi(u32 u) {
    return __uint_as_float(u & 0xffff0000u);
}
__device__ __forceinline__ float loadf(const void* p, long i, int f32) {
    return f32 ? ((const float*)p)[i] : bf2f(((const u16*)p)[i]);
}
// extract bf16 element i (0..7) from a uint4 (compile-time i folds to regs)
__device__ __forceinline__ float pick8(uint4 q, int i) {
    u32 w = (i >> 1) == 0 ? q.x : (i >> 1) == 1 ? q.y : (i >> 1) == 2 ? q.z : q.w;
    return (i & 1) ? bfhi(w) : bflo(w);
}
__device__ __forceinline__ float fsigm(float x) {
    return 1.f / (1.f + __expf(-x));
}
__device__ __forceinline__ float ftanh(float x) {
    return 1.f - 2.f / (__expf(2.f * x) + 1.f);
}
__device__ __forceinline__ float lse2(float x, float y) {
    float m = fmaxf(x, y);
    return m + logf(expf(x - m) + expf(y - m));
}
// fast lse2 for the CRF scan hot loop (hw exp/log)
__device__ __forceinline__ float lse2f(float x, float y) {
    float m = fmaxf(x, y);
    return m + __logf(__expf(x - m) + __expf(y - m));
}
// swizzled h-buffer index (u16 units)
__device__ __forceinline__ int hswz(int m, int k) {
    return m * 128 + ((((k >> 3) + m) & 15) << 3) + (k & 7);
}
__device__ __forceinline__ u32 pack2(float lo, float hi) {
    return ((u32)f2bf(hi) << 16) | (u32)f2bf(lo);
}

// ---------------------------------------------------------------------------
// Kernel 0: dtype detector (proven R4+). flag=1 => float inputs are f32.
// ---------------------------------------------------------------------------
__global__ void detect_kernel(const void* we, int* flag) {
    if (threadIdx.x == 0 && blockIdx.x == 0) {
        const u16* p = (const u16*)we;
        int big = 0;
        for (int i = 0; i < 256; ++i) {
            float a = fabsf(bf2f(p[i]));
            if (!(a < 2.f)) big++;   // counts NaN too
        }
        *flag = (big > 16) ? 1 : 0;
    }
}

// ---------------------------------------------------------------------------
// Kernel 1 (R11, proven): MFMA gather+GEMM, batched 2-wide staging loads.
// ---------------------------------------------------------------------------
#define LDA 40   // u16 stride per m-row in LDS

__global__ __launch_bounds__(256) void gemm_xs_kernel(
    const int* __restrict__ sents, const int* __restrict__ masks,
    const int* __restrict__ lens,
    const void* __restrict__ word_embed,
    const void* __restrict__ mask_embed,
    const void* __restrict__ w_ih_f, const void* __restrict__ w_ih_b,
    const void* __restrict__ b_ih_f, const void* __restrict__ b_hh_f,
    const void* __restrict__ b_ih_b, const void* __restrict__ b_hh_b,
    const int* __restrict__ flag,
    u16* __restrict__ xsF)
{
    __shared__ __align__(16) u16 As[128 * LDA];
    __shared__ __align__(16) u16 Bs[128 * LDA];
    __shared__ int rowS[128];
    __shared__ int rowM[128];

    int f32 = *flag;
    int tid = threadIdx.x;
    int mBase = blockIdx.y * 128;
    int jGlob = blockIdx.x * 128;    // [0,1024), 128-tile stays in one dir
    int dir = jGlob >> 9;
    int jj = jGlob & 511;
    const void* w_ih = dir ? w_ih_b : w_ih_f;
    const void* b_ih = dir ? b_ih_b : b_ih_f;
    const void* b_hh = dir ? b_hh_b : b_hh_f;

    int b = mBase >> 8;              // one batch per block (128 | 256)
    int posBase = mBase & 255;
    int len = lens[b];

    if (tid < 128) {
        int i = mBase + tid;
        rowS[tid] = sents[i] * 300;
        rowM[tid] = masks[i] * 50;
    }
    int wv = tid >> 6, lane = tid & 63;
    int quad = lane >> 4, col = lane & 15;
    int mS = tid >> 4;               // staging row for this thread
    int k2S = (tid & 15) << 1;       // staging k-pair base
    f32x4 acc[2][8] = {};
    __syncthreads();

    for (int kt = 0; kt < 11; ++kt) {
        int k0 = kt * 32;
        u32 aR[8], bR[8];
        if (f32) {
#pragma unroll
            for (int e = 0; e < 8; ++e) {
                int m = mS + e * 16;
                int gk = k0 + k2S;
                float2 v = make_float2(0.f, 0.f);
                if (gk < 300)
                    v = *(const float2*)((const float*)word_embed + rowS[m] + gk);
                else if (gk < 350)
                    v = *(const float2*)((const float*)mask_embed + rowM[m] + gk - 300);
                aR[e] = pack2(v.x, v.y);
                float2 w2 = make_float2(0.f, 0.f);
                if (gk < 350)
                    w2 = *(const float2*)((const float*)w_ih + (long)(jj + m) * 350 + gk);
                bR[e] = pack2(w2.x, w2.y);
            }
        } else {
#pragma unroll
            for (int e = 0; e < 8; ++e) {
                int m = mS + e * 16;
                int gk = k0 + k2S;
                u32 v = 0;
                if (gk < 300)
                    v = *(const u32*)((const u16*)word_embed + rowS[m] + gk);
                else if (gk < 350)
                    v = *(const u32*)((const u16*)mask_embed + rowM[m] + gk - 300);
                aR[e] = v;
                u32 w2 = 0;
                if (gk < 350)
                    w2 = *(const u32*)((const u16*)w_ih + (long)(jj + m) * 350 + gk);
                bR[e] = w2;
            }
        }
        __syncthreads();   // prior tile's fragment reads complete
#pragma unroll
        for (int e = 0; e < 8; ++e) {
            int m = mS + e * 16;
            *(u32*)&As[m * LDA + k2S] = aR[e];
            *(u32*)&Bs[m * LDA + k2S] = bR[e];
        }
        __syncthreads();
        bf16x8 af[2], bfr[8];
#pragma unroll
        for (int mt = 0; mt < 2; ++mt)
            af[mt] = *(const bf16x8*)&As[(wv * 32 + mt * 16 + col) * LDA + quad * 8];
#pragma unroll
        for (int nt = 0; nt < 8; ++nt)
            bfr[nt] = *(const bf16x8*)&Bs[(nt * 16 + col) * LDA + quad * 8];
#pragma unroll
        for (int mt = 0; mt < 2; ++mt)
#pragma unroll
            for (int nt = 0; nt < 8; ++nt)
                acc[mt][nt] = __builtin_amdgcn_mfma_f32_16x16x32_bf16(
                    af[mt], bfr[nt], acc[mt][nt], 0, 0, 0);
    }

    // epilogue: bias + scatter into R9 xsF fragment layout
    int bgv = b >> 2, quadv = b & 3;
#pragma unroll
    for (int nt = 0; nt < 8; ++nt) {
        int ng = jj + nt * 16 + col;           // gate-dim in [0,512)
        float bias = loadf(b_ih, ng, f32) + loadf(b_hh, ng, f32);
        int g = ng >> 7, dd = ng & 127;
        int wvx = dd >> 4, colv = dd & 15;
        int row = ((dir * 16 + bgv) * 8 + wvx) * 4 + g;
        int lanev = quadv * 16 + colv;
#pragma unroll
        for (int mt = 0; mt < 2; ++mt)
#pragma unroll
            for (int r = 0; r < 4; ++r) {
                int pos = posBase + wv * 32 + mt * 16 + quad * 4 + r;
                int s = dir ? (len - 1 - pos) : pos;
                if (s >= 0) {
                    long idxe = ((long)(row * 32 + (s >> 3))) * 512
                                + lanev * 8 + (s & 7);
                    xsF[idxe] = f2bf(acc[mt][nt][r] + bias);
                }
            }
    }
}

// ---------------------------------------------------------------------------
// Kernel 2 (R13): MFMA LSTM v5 — both directions co-resident in one block.
// 16 blocks x 1024 threads (16 waves): waves 0-7 run dir0, 8-15 run dir1.
// Two independent recurrence chains per SIMD fill each other's latency
// bubbles. Per-gate MFMA chain split into two 2-deep chains (accA/accB).
// ---------------------------------------------------------------------------
__global__ __launch_bounds__(1024, 1) void lstm_mfma_kernel(
    const u16* __restrict__ xsF,
    const void* __restrict__ w_hh_f, const void* __restrict__ w_hh_b,
    const int* __restrict__ lens, const int* __restrict__ flag,
    u16* __restrict__ context)
{
    int f32 = *flag;
    int bg = blockIdx.x;              // 0..15
    int tid = threadIdx.x;
    int dgrp = tid >> 9;              // direction of this wave-group
    int t9 = tid & 511;
    int w = t9 >> 6, lane = t9 & 63;
    int quad = lane >> 4, col = lane & 15;
    const void* w_hh = dgrp ? w_hh_b : w_hh_f;

    __shared__ __align__(16) u16 hbuf[2][2][16 * 128]; // [dir][parity], 16 KB
    __shared__ __align__(16) u16 hist[2][16 * 512];    // [dir][t&15][m*128+d], 32 KB
    __shared__ int len_s[4];
    __shared__ int maxlen_s;

    if (tid < 4) len_s[tid] = lens[bg * 4 + tid];
    for (int i = tid; i < 2 * 2 * 16 * 128; i += 1024) ((u16*)hbuf)[i] = 0;
    __syncthreads();
    if (tid == 0) {
        int mx = 0;
        for (int m = 0; m < 4; ++m) mx = max(mx, len_s[m]);
        maxlen_s = mx;
    }
    // zero-fill context for invalid pos: each dir-group covers its dir half
    for (int m = 0; m < 4; ++m) {
        int b = bg * 4 + m;
        int len = len_s[m];
        for (int idx = t9; idx < (Lq - len) * HDq; idx += 512) {
            int p = len + (idx >> 7);
            int d = idx & 127;
            context[((b << 8) + p) * Hq + dgrp * HDq + d] = 0;
        }
    }
    __syncthreads();
    int T16 = (maxlen_s + 15) & ~15;

    bf16x8 wfrag[4][4];
#pragma unroll
    for (int g = 0; g < 4; ++g) {
        int n = g * 128 + w * 16 + col;
#pragma unroll
        for (int c = 0; c < 4; ++c) {
            int k0 = c * 32 + quad * 8;
            bf16x8 fr;
            if (f32) {
                const float* src = (const float*)w_hh + (long)n * 128 + k0;
#pragma unroll
                for (int j = 0; j < 8; ++j) fr[j] = (short)f2bf(src[j]);
            } else {
                fr = *(const bf16x8*)((const u16*)w_hh + (long)n * 128 + k0);
            }
            wfrag[g][c] = fr;
        }
    }

    float c_st = 0.f;
    int mylen = len_s[quad];
    int mloc = quad * 4;
    int dcol = w * 16 + col;
    int rowb = ((dgrp * 16 + bg) * 8 + w) * 4;

    int nCh = T16 >> 3;
    for (int tc = 0; tc < nCh; ++tc) {
        uint4 xsq[4];
#pragma unroll
        for (int g = 0; g < 4; ++g)
            xsq[g] = *(const uint4*)(xsF + ((long)((rowb + g) * 32 + tc)) * 512
                                     + lane * 8);
#pragma unroll
        for (int u = 0; u < 8; ++u) {
            int t = tc * 8 + u;
            const u16* hb = hbuf[dgrp][t & 1];
            u16* hn = hbuf[dgrp][(t + 1) & 1];
            bf16x8 af[4];
#pragma unroll
            for (int c = 0; c < 4; ++c)
                af[c] = *(const bf16x8*)&hb[hswz(col, c * 32 + quad * 8)];
            f32x4 accA[4], accB[4];
#pragma unroll
            for (int g = 0; g < 4; ++g) {
                f32x4 a4 = {0.f, 0.f, 0.f, 0.f};
                a4[0] = pick8(xsq[g], u);
                accA[g] = a4;
                f32x4 z4 = {0.f, 0.f, 0.f, 0.f};
                accB[g] = z4;
            }
            // two 2-deep chains per gate (halved MFMA dependency depth)
#pragma unroll
            for (int g = 0; g < 4; ++g) {
                accA[g] = __builtin_amdgcn_mfma_f32_16x16x32_bf16(
                    af[0], wfrag[g][0], accA[g], 0, 0, 0);
                accB[g] = __builtin_amdgcn_mfma_f32_16x16x32_bf16(
                    af[2], wfrag[g][2], accB[g], 0, 0, 0);
            }
#pragma unroll
            for (int g = 0; g < 4; ++g) {
                accA[g] = __builtin_amdgcn_mfma_f32_16x16x32_bf16(
                    af[1], wfrag[g][1], accA[g], 0, 0, 0);
                accB[g] = __builtin_amdgcn_mfma_f32_16x16x32_bf16(
                    af[3], wfrag[g][3], accB[g], 0, 0, 0);
            }
            bool vld = (t < mylen);
            float i_ = fsigm(accA[0][0] + accB[0][0]);
            float f_ = fsigm(accA[1][0] + accB[1][0]);
            float g_ = ftanh(accA[2][0] + accB[2][0]);
            float o_ = fsigm(accA[3][0] + accB[3][0]);
            float cn = f_ * c_st + i_ * g_;
            if (vld) c_st = cn;
            u16 hnew = f2bf(o_ * ftanh(cn));
            u16 hv = vld ? hnew : hb[hswz(mloc, dcol)];
            hn[hswz(mloc, dcol)] = hv;
            if (vld) hist[dgrp][(t & 15) * 512 + quad * 128 + dcol] = hnew;
            __syncthreads();
            if ((t & 15) == 15) {
                int tb = t - 15;
                for (int idx = t9; idx < 4096; idx += 512) {
                    int tl = idx >> 8;
                    int rem = idx & 255;
                    int m = rem >> 6;
                    int d2 = (rem & 63) << 1;
                    int tt = tb + tl;
                    int len = len_s[m];
                    if (tt < len) {
                        int pos = dgrp ? (len - 1 - tt) : tt;
                        int b = bg * 4 + m;
                        u32 v = *(const u32*)&hist[dgrp][tl * 512 + m * 128 + d2];
                        *(u32*)&context[((b << 8) + pos) * Hq + dgrp * HDq + d2] = v;
                    }
                }
                __syncthreads();
            }
        }
    }
}

// ---------------------------------------------------------------------------
// Kernel 3: tavg (unchanged)
// ---------------------------------------------------------------------------
__global__ void tavg_kernel(const int* __restrict__ masks,
                            const u16* __restrict__ context,
                            float* __restrict__ tavg)
{
    int b = blockIdx.x, h = threadIdx.x;
    float s = 0.f, msum = 0.f;
    for (int l = 0; l < Lq; ++l) {
        int m = masks[(b << 8) + l];
        if (m) {
            s += (float)m * bf2f(context[(((b << 8) + l) << 8) + h]);
            msum += (float)m;
        }
    }
    tavg[(b << 8) + h] = s / msum;
}

// ---------------------------------------------------------------------------
// Kernel 4: emit — writes TRANSPOSED emit_T[(l*64+b)*2 + {0,1}]
// ---------------------------------------------------------------------------
__global__ void emit_kernel(const u16* __restrict__ context,
                            const float* __restrict__ tavg,
                            const void* __restrict__ f2t_w,
                            const void* __restrict__ f2t_b,
                            const int* __restrict__ flag,
                            float* __restrict__ emit_T)
{
    int f32 = *flag;
    int i = blockIdx.x;
    int b = i >> 8;
    int l = i & 255;
    int k = threadIdx.x;  // 0..63
    ushort4 c4 = *(const ushort4*)(context + (long)i * Hq + 4 * k);
    float4 t4 = *(const float4*)(tavg + b * Hq + 4 * k);
    float v0 = bf2f(c4.x) + t4.x, v1 = bf2f(c4.y) + t4.y;
    float v2 = bf2f(c4.z) + t4.z, v3 = bf2f(c4.w) + t4.w;
    int d = 4 * k;
    float p0 = v0 * loadf(f2t_w, d, f32) + v1 * loadf(f2t_w, d + 1, f32) +
               v2 * loadf(f2t_w, d + 2, f32) + v3 * loadf(f2t_w, d + 3, f32);
    float p1 = v0 * loadf(f2t_w, Hq + d, f32) + v1 * loadf(f2t_w, Hq + d + 1, f32) +
               v2 * loadf(f2t_w, Hq + d + 2, f32) + v3 * loadf(f2t_w, Hq + d + 3, f32);
#pragma unroll
    for (int off = 32; off >= 1; off >>= 1) {
        p0 += __shfl_down(p0, off);
        p1 += __shfl_down(p1, off);
    }
    if (k == 0) {
        float2 e = make_float2(p0 + loadf(f2t_b, 0, f32),
                               p1 + loadf(f2t_b, 1, f32));
        *(float2*)(emit_T + ((l << 6) + b) * 2) = e;
    }
}

// ---------------------------------------------------------------------------
// Kernel 5 (R12, proven): CRF forward-backward, transposed [t][b] layouts.
// ---------------------------------------------------------------------------
__global__ void crf_kernel(const float* __restrict__ emit_T,
                           const int* __restrict__ lens,
                           const void* __restrict__ trans,
                           const int* __restrict__ flag,
                           float* __restrict__ alphas_T,
                           float* __restrict__ sp_T,
                           float* __restrict__ spsum)
{
    int f32 = *flag;
    int b = threadIdx.x;
    float t00 = loadf(trans, 0, f32), t01 = loadf(trans, 1, f32);
    float t10 = loadf(trans, 2, f32), t11 = loadf(trans, 3, f32);
    int len = lens[b];

    // ---- forward scan ----
    float a0, a1;
    {
        float2 e0 = *(const float2*)(emit_T + (b << 1));
        a0 = e0.x; a1 = e0.y;
        *(float2*)(alphas_T + (b << 1)) = make_float2(a0, a1);
    }
    for (int tc = 0; tc < 32; ++tc) {
        float2 ebuf[8];
#pragma unroll
        for (int u = 0; u < 8; ++u) {
            int t = tc * 8 + u;
            ebuf[u] = *(const float2*)(emit_T + (((t << 6) + b) << 1));
        }
#pragma unroll
        for (int u = 0; u < 8; ++u) {
            int t = tc * 8 + u;
            if (t >= 1 && t < len) {
                float n0 = ebuf[u].x + lse2f(a0 + t00, a1 + t10);
                float n1 = ebuf[u].y + lse2f(a0 + t01, a1 + t11);
                a0 = n0; a1 = n1;
            }
            if (t >= 1)
                *(float2*)(alphas_T + (((t << 6) + b) << 1)) = make_float2(a0, a1);
        }
    }
    float logZ = lse2f(a0, a1);

    // ---- backward scan ----
    float b0 = 0.f, b1 = 0.f;
    float ssum = 0.f;
    {   // position L-1
        float a255 = alphas_T[((((Lq - 1) << 6) + b) << 1) + 1];
        float v = (Lq - 1 < len) ? __expf(a255 - logZ) : 0.f;
        sp_T[((Lq - 1) << 6) + b] = v; ssum += v;
    }
    for (int tc = 31; tc >= 0; --tc) {
        float2 ebuf[8];
        float abuf[8];   // alpha1 at t-1
#pragma unroll
        for (int u = 0; u < 8; ++u) {
            int t = tc * 8 + u;
            ebuf[u] = *(const float2*)(emit_T + (((t << 6) + b) << 1));
            if (t >= 1)
                abuf[u] = alphas_T[((((t - 1) << 6) + b) << 1) + 1];
        }
#pragma unroll
        for (int uu = 7; uu >= 0; --uu) {
            int t = tc * 8 + uu;
            if (t < 1) break;
            if (t < len) {
                float e0 = ebuf[uu].x, e1 = ebuf[uu].y;
                float n0 = lse2f(t00 + e0 + b0, t01 + e1 + b1);
                float n1 = lse2f(t10 + e0 + b0, t11 + e1 + b1);
                b0 = n0; b1 = n1;
            }
            float v = ((t - 1) < len) ? __expf(abuf[uu] + b1 - logZ) : 0.f;
            sp_T[((t - 1) << 6) + b] = v; ssum += v;
        }
    }
    spsum[b] = ssum;
}

// ---------------------------------------------------------------------------
// Kernel 6: sentv — reads transposed sp_T[l*64+b] (broadcast per block)
// ---------------------------------------------------------------------------
__global__ void sentv_kernel(const float* __restrict__ sp_T,
                             const u16* __restrict__ context,
                             const float* __restrict__ tavg,
                             const float* __restrict__ spsum,
                             float* __restrict__ sentv)
{
    int b = blockIdx.x, h = threadIdx.x;
    float s = 0.f;
    for (int l = 0; l < Lq; ++l)
        s += sp_T[(l << 6) + b] * bf2f(context[(((b << 8) + l) << 8) + h]);
    sentv[(b << 8) + h] = s + spsum[b] * tavg[(b << 8) + h];
}

// ---------------------------------------------------------------------------
// Kernel 7: final loss (unchanged)
// ---------------------------------------------------------------------------
__global__ void final_kernel(const float* __restrict__ sentv,
                             const float* __restrict__ spsum,
                             const void* __restrict__ f2l_w,
                             const void* __restrict__ f2l_b,
                             const void* __restrict__ trans,
                             const int* __restrict__ labels,
                             const int* __restrict__ flag,
                             void* __restrict__ out)
{
    int f32 = *flag;
    int b = threadIdx.x;  // 64 lanes
    float s0 = 0.f, s1 = 0.f, s2 = 0.f;
    for (int h = 0; h < Hq; ++h) {
        float v = sentv[(b << 8) + h];
        s0 += v * loadf(f2l_w, h, f32);
        s1 += v * loadf(f2l_w, Hq + h, f32);
        s2 += v * loadf(f2l_w, 2 * Hq + h, f32);
    }
    s0 += loadf(f2l_b, 0, f32); s1 += loadf(f2l_b, 1, f32); s2 += loadf(f2l_b, 2, f32);
    float m = fmaxf(s0, fmaxf(s1, s2));
    float lse = m + logf(expf(s0 - m) + expf(s1 - m) + expf(s2 - m));
    int lab = labels[b];
    float sc = lab == 0 ? s0 : (lab == 1 ? s1 : s2);
    float loss = lse - sc;
    float sn = spsum[b];
#pragma unroll
    for (int off = 32; off >= 1; off >>= 1) {
        loss += __shfl_down(loss, off);
        sn += __shfl_down(sn, off);
    }
    if (b == 0) {
        float cls = loss / 64.f;
        float t00 = loadf(trans, 0, f32), t01 = loadf(trans, 1, f32);
        float t10 = loadf(trans, 2, f32), t11 = loadf(trans, 3, f32);
        float pena = fmaxf(t10 - t00, 0.f) + fmaxf(t01 - t11, 0.f);
        float np = 1.0f * pena + 0.1f * (sn / 64.f);
        if (f32) {
            ((float*)out)[0] = cls;
            ((float*)out)[1] = np;
        } else {
            ((__hip_bfloat16*)out)[0] = __float2bfloat16(cls);
            ((__hip_bfloat16*)out)[1] = __float2bfloat16(np);
        }
    }
}

extern "C" void kernel_launch(void* const* d_in, const int* in_sizes, int n_in,
                              void* d_out, int out_size, void* d_ws, size_t ws_size,
                              hipStream_t stream)
{
    const int* sents  = (const int*)d_in[0];
    const int* masks  = (const int*)d_in[1];
    const int* labels = (const int*)d_in[2];
    const int* lens   = (const int*)d_in[3];
    const void* word_embed = d_in[4];
    const void* mask_embed = d_in[5];
    const void* w_ih_f = d_in[6];
    const void* w_hh_f = d_in[7];
    const void* b_ih_f = d_in[8];
    const void* b_hh_f = d_in[9];
    const void* w_ih_b = d_in[10];
    const void* w_hh_b = d_in[11];
    const void* b_ih_b = d_in[12];
    const void* b_hh_b = d_in[13];
    const void* f2t_w  = d_in[14];
    const void* f2t_b  = d_in[15];
    const void* trans  = d_in[16];
    const void* f2l_w  = d_in[17];
    const void* f2l_b  = d_in[18];

    // workspace layout: identical byte budget to R5-R12's proven 42.4 MB
    char* wsb = (char*)d_ws;
    size_t off = 33554432;                   // xsF: 1024*32*512 bf16 = 32 MB
    u16*   xsF     = (u16*)wsb;
    u16*   context = (u16*)(wsb + off);      off += 8388608;
    float* tavg    = (float*)(wsb + off);    off += 65536;
    float* alphas  = (float*)(wsb + off);    off += 131072;
    float* emit    = (float*)(wsb + off);    off += 131072;
    float* sp      = (float*)(wsb + off);    off += 65536;
    float* spsum   = (float*)(wsb + off);    off += 4096;
    float* sentv   = (float*)(wsb + off);    off += 65536;
    int*   flag    = (int*)(wsb + off);

    detect_kernel<<<1, 64, 0, stream>>>(word_embed, flag);

    gemm_xs_kernel<<<dim3(8, 128), 256, 0, stream>>>(
        sents, masks, lens, word_embed, mask_embed,
        w_ih_f, w_ih_b, b_ih_f, b_hh_f, b_ih_b, b_hh_b, flag, xsF);

    lstm_mfma_kernel<<<16, 1024, 0, stream>>>(
        xsF, w_hh_f, w_hh_b, lens, flag, context);

    tavg_kernel<<<Bq, 256, 0, stream>>>(masks, context, tavg);

    emit_kernel<<<Bq * Lq, 64, 0, stream>>>(context, tavg, f2t_w, f2t_b, flag, emit);

    crf_kernel<<<1, 64, 0, stream>>>(emit, lens, trans, flag, alphas, sp, spsum);

    sentv_kernel<<<Bq, 256, 0, stream>>>(sp, context, tavg, spsum, sentv);

    final_kernel<<<1, 64, 0, stream>>>(sentv, spsum, f2l_w, f2l_b, trans, labels,
                                       flag, d_out);
}

// Round 14
// 589.575 us; speedup vs baseline: 1.5397x; 1.5397x over previous
//
#include <hip/hip_runtime.h>
#include <hip/hip_bf16.h>

#define Bq 64
#define Lq 256
#define Dq 350
#define HDq 128
#define Hq 256
#define G4 512   // 4*HD

typedef unsigned short u16;
typedef unsigned int u32;
typedef __attribute__((ext_vector_type(8))) short bf16x8;
typedef __attribute__((ext_vector_type(4))) float f32x4;

__device__ __forceinline__ float bf2f(u16 u) {
    return __uint_as_float(((u32)u) << 16);
}
__device__ __forceinline__ u16 f2bf(float f) {
    __hip_bfloat16 h = __float2bfloat16(f);
    return *(u16*)&h;
}
__device__ __forceinline__ float bflo(u32 u) {
    return __uint_as_float(u << 16);
}
__device__ __forceinline__ float bfhi(u32 u) {
    return __uint_as_float(u & 0xffff0000u);
}
__device__ __forceinline__ float loadf(const void* p, long i, int f32) {
    return f32 ? ((const float*)p)[i] : bf2f(((const u16*)p)[i]);
}
// extract bf16 element i (0..7) from a uint4 (compile-time i folds to regs)
__device__ __forceinline__ float pick8(uint4 q, int i) {
    u32 w = (i >> 1) == 0 ? q.x : (i >> 1) == 1 ? q.y : (i >> 1) == 2 ? q.z : q.w;
    return (i & 1) ? bfhi(w) : bflo(w);
}
__device__ __forceinline__ float fsigm(float x) {
    return 1.f / (1.f + __expf(-x));
}
__device__ __forceinline__ float ftanh(float x) {
    return 1.f - 2.f / (__expf(2.f * x) + 1.f);
}
__device__ __forceinline__ float lse2(float x, float y) {
    float m = fmaxf(x, y);
    return m + logf(expf(x - m) + expf(y - m));
}
// fast lse2 for the CRF scan hot loop (hw exp/log)
__device__ __forceinline__ float lse2f(float x, float y) {
    float m = fmaxf(x, y);
    return m + __logf(__expf(x - m) + __expf(y - m));
}
// swizzled h-buffer index (u16 units)
__device__ __forceinline__ int hswz(int m, int k) {
    return m * 128 + ((((k >> 3) + m) & 15) << 3) + (k & 7);
}
__device__ __forceinline__ u32 pack2(float lo, float hi) {
    return ((u32)f2bf(hi) << 16) | (u32)f2bf(lo);
}

// ---------------------------------------------------------------------------
// Kernel 0: dtype detector (proven R4+). flag=1 => float inputs are f32.
// ---------------------------------------------------------------------------
__global__ void detect_kernel(const void* we, int* flag) {
    if (threadIdx.x == 0 && blockIdx.x == 0) {
        const u16* p = (const u16*)we;
        int big = 0;
        for (int i = 0; i < 256; ++i) {
            float a = fabsf(bf2f(p[i]));
            if (!(a < 2.f)) big++;   // counts NaN too
        }
        *flag = (big > 16) ? 1 : 0;
    }
}

// ---------------------------------------------------------------------------
// Kernel 1 (R11, proven): MFMA gather+GEMM, batched 2-wide staging loads.
// ---------------------------------------------------------------------------
#define LDA 40   // u16 stride per m-row in LDS

__global__ __launch_bounds__(256) void gemm_xs_kernel(
    const int* __restrict__ sents, const int* __restrict__ masks,
    const int* __restrict__ lens,
    const void* __restrict__ word_embed,
    const void* __restrict__ mask_embed,
    const void* __restrict__ w_ih_f, const void* __restrict__ w_ih_b,
    const void* __restrict__ b_ih_f, const void* __restrict__ b_hh_f,
    const void* __restrict__ b_ih_b, const void* __restrict__ b_hh_b,
    const int* __restrict__ flag,
    u16* __restrict__ xsF)
{
    __shared__ __align__(16) u16 As[128 * LDA];
    __shared__ __align__(16) u16 Bs[128 * LDA];
    __shared__ int rowS[128];
    __shared__ int rowM[128];

    int f32 = *flag;
    int tid = threadIdx.x;
    int mBase = blockIdx.y * 128;
    int jGlob = blockIdx.x * 128;    // [0,1024), 128-tile stays in one dir
    int dir = jGlob >> 9;
    int jj = jGlob & 511;
    const void* w_ih = dir ? w_ih_b : w_ih_f;
    const void* b_ih = dir ? b_ih_b : b_ih_f;
    const void* b_hh = dir ? b_hh_b : b_hh_f;

    int b = mBase >> 8;              // one batch per block (128 | 256)
    int posBase = mBase & 255;
    int len = lens[b];

    if (tid < 128) {
        int i = mBase + tid;
        rowS[tid] = sents[i] * 300;
        rowM[tid] = masks[i] * 50;
    }
    int wv = tid >> 6, lane = tid & 63;
    int quad = lane >> 4, col = lane & 15;
    int mS = tid >> 4;               // staging row for this thread
    int k2S = (tid & 15) << 1;       // staging k-pair base
    f32x4 acc[2][8] = {};
    __syncthreads();

    for (int kt = 0; kt < 11; ++kt) {
        int k0 = kt * 32;
        u32 aR[8], bR[8];
        if (f32) {
#pragma unroll
            for (int e = 0; e < 8; ++e) {
                int m = mS + e * 16;
                int gk = k0 + k2S;
                float2 v = make_float2(0.f, 0.f);
                if (gk < 300)
                    v = *(const float2*)((const float*)word_embed + rowS[m] + gk);
                else if (gk < 350)
                    v = *(const float2*)((const float*)mask_embed + rowM[m] + gk - 300);
                aR[e] = pack2(v.x, v.y);
                float2 w2 = make_float2(0.f, 0.f);
                if (gk < 350)
                    w2 = *(const float2*)((const float*)w_ih + (long)(jj + m) * 350 + gk);
                bR[e] = pack2(w2.x, w2.y);
            }
        } else {
#pragma unroll
            for (int e = 0; e < 8; ++e) {
                int m = mS + e * 16;
                int gk = k0 + k2S;
                u32 v = 0;
                if (gk < 300)
                    v = *(const u32*)((const u16*)word_embed + rowS[m] + gk);
                else if (gk < 350)
                    v = *(const u32*)((const u16*)mask_embed + rowM[m] + gk - 300);
                aR[e] = v;
                u32 w2 = 0;
                if (gk < 350)
                    w2 = *(const u32*)((const u16*)w_ih + (long)(jj + m) * 350 + gk);
                bR[e] = w2;
            }
        }
        __syncthreads();   // prior tile's fragment reads complete
#pragma unroll
        for (int e = 0; e < 8; ++e) {
            int m = mS + e * 16;
            *(u32*)&As[m * LDA + k2S] = aR[e];
            *(u32*)&Bs[m * LDA + k2S] = bR[e];
        }
        __syncthreads();
        bf16x8 af[2], bfr[8];
#pragma unroll
        for (int mt = 0; mt < 2; ++mt)
            af[mt] = *(const bf16x8*)&As[(wv * 32 + mt * 16 + col) * LDA + quad * 8];
#pragma unroll
        for (int nt = 0; nt < 8; ++nt)
            bfr[nt] = *(const bf16x8*)&Bs[(nt * 16 + col) * LDA + quad * 8];
#pragma unroll
        for (int mt = 0; mt < 2; ++mt)
#pragma unroll
            for (int nt = 0; nt < 8; ++nt)
                acc[mt][nt] = __builtin_amdgcn_mfma_f32_16x16x32_bf16(
                    af[mt], bfr[nt], acc[mt][nt], 0, 0, 0);
    }

    // epilogue: bias + scatter into R9 xsF fragment layout
    int bgv = b >> 2, quadv = b & 3;
#pragma unroll
    for (int nt = 0; nt < 8; ++nt) {
        int ng = jj + nt * 16 + col;           // gate-dim in [0,512)
        float bias = loadf(b_ih, ng, f32) + loadf(b_hh, ng, f32);
        int g = ng >> 7, dd = ng & 127;
        int wvx = dd >> 4, colv = dd & 15;
        int row = ((dir * 16 + bgv) * 8 + wvx) * 4 + g;
        int lanev = quadv * 16 + colv;
#pragma unroll
        for (int mt = 0; mt < 2; ++mt)
#pragma unroll
            for (int r = 0; r < 4; ++r) {
                int pos = posBase + wv * 32 + mt * 16 + quad * 4 + r;
                int s = dir ? (len - 1 - pos) : pos;
                if (s >= 0) {
                    long idxe = ((long)(row * 32 + (s >> 3))) * 512
                                + lanev * 8 + (s & 7);
                    xsF[idxe] = f2bf(acc[mt][nt][r] + bias);
                }
            }
    }
}

// ---------------------------------------------------------------------------
// Kernel 2: MFMA LSTM v4 (R12-exact, proven 193 us). 32 blocks x 512 thr.
// ---------------------------------------------------------------------------
__global__ __launch_bounds__(512, 1) void lstm_mfma_kernel(
    const u16* __restrict__ xsF,
    const void* __restrict__ w_hh_f, const void* __restrict__ w_hh_b,
    const int* __restrict__ lens, const int* __restrict__ flag,
    u16* __restrict__ context)
{
    int f32 = *flag;
    int blk = blockIdx.x;
    int dir = blk >> 4, bg = blk & 15;
    int tid = threadIdx.x;
    int w = tid >> 6, lane = tid & 63;
    int quad = lane >> 4, col = lane & 15;
    const void* w_hh = dir ? w_hh_b : w_hh_f;

    __shared__ __align__(16) u16 hbuf[2][16 * 128];  // swizzled dbuf, 8 KB
    __shared__ __align__(16) u16 hist[16 * 512];     // [t&15][m*128+d], 16 KB
    __shared__ int len_s[4];
    __shared__ int maxlen_s;

    if (tid < 4) len_s[tid] = lens[bg * 4 + tid];
    for (int i = tid; i < 2 * 16 * 128; i += 512) ((u16*)hbuf)[i] = 0;
    __syncthreads();
    if (tid == 0) {
        int mx = 0;
        for (int m = 0; m < 4; ++m) mx = max(mx, len_s[m]);
        maxlen_s = mx;
    }
    for (int m = 0; m < 4; ++m) {
        int b = bg * 4 + m;
        int len = len_s[m];
        for (int idx = tid; idx < (Lq - len) * HDq; idx += 512) {
            int p = len + (idx >> 7);
            int d = idx & 127;
            context[((b << 8) + p) * Hq + dir * HDq + d] = 0;
        }
    }
    __syncthreads();
    int T16 = (maxlen_s + 15) & ~15;

    bf16x8 wfrag[4][4];
#pragma unroll
    for (int g = 0; g < 4; ++g) {
        int n = g * 128 + w * 16 + col;
#pragma unroll
        for (int c = 0; c < 4; ++c) {
            int k0 = c * 32 + quad * 8;
            bf16x8 fr;
            if (f32) {
                const float* src = (const float*)w_hh + (long)n * 128 + k0;
#pragma unroll
                for (int j = 0; j < 8; ++j) fr[j] = (short)f2bf(src[j]);
            } else {
                fr = *(const bf16x8*)((const u16*)w_hh + (long)n * 128 + k0);
            }
            wfrag[g][c] = fr;
        }
    }

    float c_st = 0.f;
    int mylen = len_s[quad];
    int mloc = quad * 4;
    int dcol = w * 16 + col;
    int rowb = ((dir * 16 + bg) * 8 + w) * 4;

    int nCh = T16 >> 3;
    for (int tc = 0; tc < nCh; ++tc) {
        uint4 xsq[4];
#pragma unroll
        for (int g = 0; g < 4; ++g)
            xsq[g] = *(const uint4*)(xsF + ((long)((rowb + g) * 32 + tc)) * 512
                                     + lane * 8);
#pragma unroll
        for (int u = 0; u < 8; ++u) {
            int t = tc * 8 + u;
            const u16* hb = hbuf[t & 1];
            u16* hn = hbuf[(t + 1) & 1];
            bf16x8 af[4];
#pragma unroll
            for (int c = 0; c < 4; ++c)
                af[c] = *(const bf16x8*)&hb[hswz(col, c * 32 + quad * 8)];
            f32x4 acc[4];
#pragma unroll
            for (int g = 0; g < 4; ++g) {
                f32x4 a4 = {0.f, 0.f, 0.f, 0.f};
                a4[0] = pick8(xsq[g], u);
                acc[g] = a4;
            }
#pragma unroll
            for (int c = 0; c < 4; ++c)
#pragma unroll
                for (int g = 0; g < 4; ++g)
                    acc[g] = __builtin_amdgcn_mfma_f32_16x16x32_bf16(
                        af[c], wfrag[g][c], acc[g], 0, 0, 0);
            bool vld = (t < mylen);
            float i_ = fsigm(acc[0][0]);
            float f_ = fsigm(acc[1][0]);
            float g_ = ftanh(acc[2][0]);
            float o_ = fsigm(acc[3][0]);
            float cn = f_ * c_st + i_ * g_;
            if (vld) c_st = cn;
            u16 hnew = f2bf(o_ * ftanh(cn));
            u16 hv = vld ? hnew : hb[hswz(mloc, dcol)];
            hn[hswz(mloc, dcol)] = hv;
            if (vld) hist[(t & 15) * 512 + quad * 128 + dcol] = hnew;
            __syncthreads();
            if ((t & 15) == 15) {
                int tb = t - 15;
                for (int idx = tid; idx < 4096; idx += 512) {
                    int tl = idx >> 8;
                    int rem = idx & 255;
                    int m = rem >> 6;
                    int d2 = (rem & 63) << 1;
                    int tt = tb + tl;
                    int len = len_s[m];
                    if (tt < len) {
                        int pos = dir ? (len - 1 - tt) : tt;
                        int b = bg * 4 + m;
                        u32 v = *(const u32*)&hist[tl * 512 + m * 128 + d2];
                        *(u32*)&context[((b << 8) + pos) * Hq + dir * HDq + d2] = v;
                    }
                }
                __syncthreads();
            }
        }
    }
}

// ---------------------------------------------------------------------------
// Kernel 3 (R14): tavg — masks row preloaded to LDS (kills 256 dependent
// scalar global loads per block); mask==0 rows skip wave-uniformly as before.
// ---------------------------------------------------------------------------
__global__ void tavg_kernel(const int* __restrict__ masks,
                            const u16* __restrict__ context,
                            float* __restrict__ tavg)
{
    __shared__ int m_s[Lq];
    int b = blockIdx.x, h = threadIdx.x;
    m_s[h] = masks[(b << 8) + h];
    __syncthreads();
    float s = 0.f, msum = 0.f;
    for (int l = 0; l < Lq; ++l) {
        int m = m_s[l];
        if (m) {
            s += (float)m * bf2f(context[(((b << 8) + l) << 8) + h]);
            msum += (float)m;
        }
    }
    tavg[(b << 8) + h] = s / msum;
}

// ---------------------------------------------------------------------------
// Kernel 4 (R14): emit — 4 rows per block (one per wave), 4096 blocks.
// Writes TRANSPOSED emit_T[(l*64+b)*2 + {0,1}].
// ---------------------------------------------------------------------------
__global__ void emit_kernel(const u16* __restrict__ context,
                            const float* __restrict__ tavg,
                            const void* __restrict__ f2t_w,
                            const void* __restrict__ f2t_b,
                            const int* __restrict__ flag,
                            float* __restrict__ emit_T)
{
    int f32 = *flag;
    int wv = threadIdx.x >> 6;
    int i = (blockIdx.x << 2) + wv;
    int b = i >> 8;
    int l = i & 255;
    int k = threadIdx.x & 63;  // 0..63
    ushort4 c4 = *(const ushort4*)(context + (long)i * Hq + 4 * k);
    float4 t4 = *(const float4*)(tavg + b * Hq + 4 * k);
    float v0 = bf2f(c4.x) + t4.x, v1 = bf2f(c4.y) + t4.y;
    float v2 = bf2f(c4.z) + t4.z, v3 = bf2f(c4.w) + t4.w;
    int d = 4 * k;
    float p0 = v0 * loadf(f2t_w, d, f32) + v1 * loadf(f2t_w, d + 1, f32) +
               v2 * loadf(f2t_w, d + 2, f32) + v3 * loadf(f2t_w, d + 3, f32);
    float p1 = v0 * loadf(f2t_w, Hq + d, f32) + v1 * loadf(f2t_w, Hq + d + 1, f32) +
               v2 * loadf(f2t_w, Hq + d + 2, f32) + v3 * loadf(f2t_w, Hq + d + 3, f32);
#pragma unroll
    for (int off = 32; off >= 1; off >>= 1) {
        p0 += __shfl_down(p0, off);
        p1 += __shfl_down(p1, off);
    }
    if (k == 0) {
        float2 e = make_float2(p0 + loadf(f2t_b, 0, f32),
                               p1 + loadf(f2t_b, 1, f32));
        *(float2*)(emit_T + ((l << 6) + b) * 2) = e;
    }
}

// ---------------------------------------------------------------------------
// Kernel 5 (R12, proven): CRF forward-backward, transposed [t][b] layouts.
// ---------------------------------------------------------------------------
__global__ void crf_kernel(const float* __restrict__ emit_T,
                           const int* __restrict__ lens,
                           const void* __restrict__ trans,
                           const int* __restrict__ flag,
                           float* __restrict__ alphas_T,
                           float* __restrict__ sp_T,
                           float* __restrict__ spsum)
{
    int f32 = *flag;
    int b = threadIdx.x;
    float t00 = loadf(trans, 0, f32), t01 = loadf(trans, 1, f32);
    float t10 = loadf(trans, 2, f32), t11 = loadf(trans, 3, f32);
    int len = lens[b];

    // ---- forward scan ----
    float a0, a1;
    {
        float2 e0 = *(const float2*)(emit_T + (b << 1));
        a0 = e0.x; a1 = e0.y;
        *(float2*)(alphas_T + (b << 1)) = make_float2(a0, a1);
    }
    for (int tc = 0; tc < 32; ++tc) {
        float2 ebuf[8];
#pragma unroll
        for (int u = 0; u < 8; ++u) {
            int t = tc * 8 + u;
            ebuf[u] = *(const float2*)(emit_T + (((t << 6) + b) << 1));
        }
#pragma unroll
        for (int u = 0; u < 8; ++u) {
            int t = tc * 8 + u;
            if (t >= 1 && t < len) {
                float n0 = ebuf[u].x + lse2f(a0 + t00, a1 + t10);
                float n1 = ebuf[u].y + lse2f(a0 + t01, a1 + t11);
                a0 = n0; a1 = n1;
            }
            if (t >= 1)
                *(float2*)(alphas_T + (((t << 6) + b) << 1)) = make_float2(a0, a1);
        }
    }
    float logZ = lse2f(a0, a1);

    // ---- backward scan ----
    float b0 = 0.f, b1 = 0.f;
    float ssum = 0.f;
    {   // position L-1
        float a255 = alphas_T[((((Lq - 1) << 6) + b) << 1) + 1];
        float v = (Lq - 1 < len) ? __expf(a255 - logZ) : 0.f;
        sp_T[((Lq - 1) << 6) + b] = v; ssum += v;
    }
    for (int tc = 31; tc >= 0; --tc) {
        float2 ebuf[8];
        float abuf[8];   // alpha1 at t-1
#pragma unroll
        for (int u = 0; u < 8; ++u) {
            int t = tc * 8 + u;
            ebuf[u] = *(const float2*)(emit_T + (((t << 6) + b) << 1));
            if (t >= 1)
                abuf[u] = alphas_T[((((t - 1) << 6) + b) << 1) + 1];
        }
#pragma unroll
        for (int uu = 7; uu >= 0; --uu) {
            int t = tc * 8 + uu;
            if (t < 1) break;
            if (t < len) {
                float e0 = ebuf[uu].x, e1 = ebuf[uu].y;
                float n0 = lse2f(t00 + e0 + b0, t01 + e1 + b1);
                float n1 = lse2f(t10 + e0 + b0, t11 + e1 + b1);
                b0 = n0; b1 = n1;
            }
            float v = ((t - 1) < len) ? __expf(abuf[uu] + b1 - logZ) : 0.f;
            sp_T[((t - 1) << 6) + b] = v; ssum += v;
        }
    }
    spsum[b] = ssum;
}

// ---------------------------------------------------------------------------
// Kernel 6 (R14): sentv — sp row preloaded to LDS, context loop unrolled 4x
// (4 independent row loads batched per wait).
// ---------------------------------------------------------------------------
__global__ void sentv_kernel(const float* __restrict__ sp_T,
                             const u16* __restrict__ context,
                             const float* __restrict__ tavg,
                             const float* __restrict__ spsum,
                             float* __restrict__ sentv)
{
    __shared__ float sp_s[Lq];
    int b = blockIdx.x, h = threadIdx.x;
    sp_s[h] = sp_T[(h << 6) + b];
    __syncthreads();
    float s = 0.f;
    for (int l0 = 0; l0 < Lq; l0 += 4) {
        u16 c0 = context[(((b << 8) + l0 + 0) << 8) + h];
        u16 c1 = context[(((b << 8) + l0 + 1) << 8) + h];
        u16 c2 = context[(((b << 8) + l0 + 2) << 8) + h];
        u16 c3 = context[(((b << 8) + l0 + 3) << 8) + h];
        s += sp_s[l0 + 0] * bf2f(c0);
        s += sp_s[l0 + 1] * bf2f(c1);
        s += sp_s[l0 + 2] * bf2f(c2);
        s += sp_s[l0 + 3] * bf2f(c3);
    }
    sentv[(b << 8) + h] = s + spsum[b] * tavg[(b << 8) + h];
}

// ---------------------------------------------------------------------------
// Kernel 7: final loss (unchanged)
// ---------------------------------------------------------------------------
__global__ void final_kernel(const float* __restrict__ sentv,
                             const float* __restrict__ spsum,
                             const void* __restrict__ f2l_w,
                             const void* __restrict__ f2l_b,
                             const void* __restrict__ trans,
                             const int* __restrict__ labels,
                             const int* __restrict__ flag,
                             void* __restrict__ out)
{
    int f32 = *flag;
    int b = threadIdx.x;  // 64 lanes
    float s0 = 0.f, s1 = 0.f, s2 = 0.f;
    for (int h = 0; h < Hq; ++h) {
        float v = sentv[(b << 8) + h];
        s0 += v * loadf(f2l_w, h, f32);
        s1 += v * loadf(f2l_w, Hq + h, f32);
        s2 += v * loadf(f2l_w, 2 * Hq + h, f32);
    }
    s0 += loadf(f2l_b, 0, f32); s1 += loadf(f2l_b, 1, f32); s2 += loadf(f2l_b, 2, f32);
    float m = fmaxf(s0, fmaxf(s1, s2));
    float lse = m + logf(expf(s0 - m) + expf(s1 - m) + expf(s2 - m));
    int lab = labels[b];
    float sc = lab == 0 ? s0 : (lab == 1 ? s1 : s2);
    float loss = lse - sc;
    float sn = spsum[b];
#pragma unroll
    for (int off = 32; off >= 1; off >>= 1) {
        loss += __shfl_down(loss, off);
        sn += __shfl_down(sn, off);
    }
    if (b == 0) {
        float cls = loss / 64.f;
        float t00 = loadf(trans, 0, f32), t01 = loadf(trans, 1, f32);
        float t10 = loadf(trans, 2, f32), t11 = loadf(trans, 3, f32);
        float pena = fmaxf(t10 - t00, 0.f) + fmaxf(t01 - t11, 0.f);
        float np = 1.0f * pena + 0.1f * (sn / 64.f);
        if (f32) {
            ((float*)out)[0] = cls;
            ((float*)out)[1] = np;
        } else {
            ((__hip_bfloat16*)out)[0] = __float2bfloat16(cls);
            ((__hip_bfloat16*)out)[1] = __float2bfloat16(np);
        }
    }
}

extern "C" void kernel_launch(void* const* d_in, const int* in_sizes, int n_in,
                              void* d_out, int out_size, void* d_ws, size_t ws_size,
                              hipStream_t stream)
{
    const int* sents  = (const int*)d_in[0];
    const int* masks  = (const int*)d_in[1];
    const int* labels = (const int*)d_in[2];
    const int* lens   = (const int*)d_in[3];
    const void* word_embed = d_in[4];
    const void* mask_embed = d_in[5];
    const void* w_ih_f = d_in[6];
    const void* w_hh_f = d_in[7];
    const void* b_ih_f = d_in[8];
    const void* b_hh_f = d_in[9];
    const void* w_ih_b = d_in[10];
    const void* w_hh_b = d_in[11];
    const void* b_ih_b = d_in[12];
    const void* b_hh_b = d_in[13];
    const void* f2t_w  = d_in[14];
    const void* f2t_b  = d_in[15];
    const void* trans  = d_in[16];
    const void* f2l_w  = d_in[17];
    const void* f2l_b  = d_in[18];

    // workspace layout: identical byte budget to R5-R12's proven 42.4 MB
    char* wsb = (char*)d_ws;
    size_t off = 33554432;                   // xsF: 1024*32*512 bf16 = 32 MB
    u16*   xsF     = (u16*)wsb;
    u16*   context = (u16*)(wsb + off);      off += 8388608;
    float* tavg    = (float*)(wsb + off);    off += 65536;
    float* alphas  = (float*)(wsb + off);    off += 131072;
    float* emit    = (float*)(wsb + off);    off += 131072;
    float* sp      = (float*)(wsb + off);    off += 65536;
    float* spsum   = (float*)(wsb + off);    off += 4096;
    float* sentv   = (float*)(wsb + off);    off += 65536;
    int*   flag    = (int*)(wsb + off);

    detect_kernel<<<1, 64, 0, stream>>>(word_embed, flag);

    gemm_xs_kernel<<<dim3(8, 128), 256, 0, stream>>>(
        sents, masks, lens, word_embed, mask_embed,
        w_ih_f, w_ih_b, b_ih_f, b_hh_f, b_ih_b, b_hh_b, flag, xsF);

    lstm_mfma_kernel<<<32, 512, 0, stream>>>(
        xsF, w_hh_f, w_hh_b, lens, flag, context);

    tavg_kernel<<<Bq, 256, 0, stream>>>(masks, context, tavg);

    emit_kernel<<<Bq * Lq / 4, 256, 0, stream>>>(context, tavg, f2t_w, f2t_b, flag, emit);

    crf_kernel<<<1, 64, 0, stream>>>(emit, lens, trans, flag, alphas, sp, spsum);

    sentv_kernel<<<Bq, 256, 0, stream>>>(sp, context, tavg, spsum, sentv);

    final_kernel<<<1, 64, 0, stream>>>(sentv, spsum, f2l_w, f2l_b, trans, labels,
                                       flag, d_out);
}

// Round 15
// 535.621 us; speedup vs baseline: 1.6948x; 1.1007x over previous
//
#include <hip/hip_runtime.h>
#include <hip/hip_bf16.h>

#define Bq 64
#define Lq 256
#define Dq 350
#define HDq 128
#define Hq 256
#define G4 512   // 4*HD

typedef unsigned short u16;
typedef unsigned int u32;
typedef __attribute__((ext_vector_type(8))) short bf16x8;
typedef __attribute__((ext_vector_type(4))) float f32x4;

__device__ __forceinline__ float bf2f(u16 u) {
    return __uint_as_float(((u32)u) << 16);
}
__device__ __forceinline__ u16 f2bf(float f) {
    __hip_bfloat16 h = __float2bfloat16(f);
    return *(u16*)&h;
}
__device__ __forceinline__ float bflo(u32 u) {
    return __uint_as_float(u << 16);
}
__device__ __forceinline__ float bfhi(u32 u) {
    return __uint_as_float(u & 0xffff0000u);
}
__device__ __forceinline__ float loadf(const void* p, long i, int f32) {
    return f32 ? ((const float*)p)[i] : bf2f(((const u16*)p)[i]);
}
// extract bf16 element i (0..7) from a uint4 (compile-time i folds to regs)
__device__ __forceinline__ float pick8(uint4 q, int i) {
    u32 w = (i >> 1) == 0 ? q.x : (i >> 1) == 1 ? q.y : (i >> 1) == 2 ? q.z : q.w;
    return (i & 1) ? bfhi(w) : bflo(w);
}
__device__ __forceinline__ float fsigm(float x) {
    return 1.f / (1.f + __expf(-x));
}
__device__ __forceinline__ float ftanh(float x) {
    return 1.f - 2.f / (__expf(2.f * x) + 1.f);
}
__device__ __forceinline__ float lse2f(float x, float y) {
    float m = fmaxf(x, y);
    return m + __logf(__expf(x - m) + __expf(y - m));
}
// swizzled h-buffer index (u16 units)
__device__ __forceinline__ int hswz(int m, int k) {
    return m * 128 + ((((k >> 3) + m) & 15) << 3) + (k & 7);
}
__device__ __forceinline__ u32 pack2(float lo, float hi) {
    return ((u32)f2bf(hi) << 16) | (u32)f2bf(lo);
}

// ---------------------------------------------------------------------------
// Kernel 0: dtype detector (proven R4+). flag=1 => float inputs are f32.
// ---------------------------------------------------------------------------
__global__ void detect_kernel(const void* we, int* flag) {
    if (threadIdx.x == 0 && blockIdx.x == 0) {
        const u16* p = (const u16*)we;
        int big = 0;
        for (int i = 0; i < 256; ++i) {
            float a = fabsf(bf2f(p[i]));
            if (!(a < 2.f)) big++;   // counts NaN too
        }
        *flag = (big > 16) ? 1 : 0;
    }
}

// ---------------------------------------------------------------------------
// Kernel 1 (R11, proven): MFMA gather+GEMM, batched 2-wide staging loads.
// ---------------------------------------------------------------------------
#define LDA 40   // u16 stride per m-row in LDS

__global__ __launch_bounds__(256) void gemm_xs_kernel(
    const int* __restrict__ sents, const int* __restrict__ masks,
    const int* __restrict__ lens,
    const void* __restrict__ word_embed,
    const void* __restrict__ mask_embed,
    const void* __restrict__ w_ih_f, const void* __restrict__ w_ih_b,
    const void* __restrict__ b_ih_f, const void* __restrict__ b_hh_f,
    const void* __restrict__ b_ih_b, const void* __restrict__ b_hh_b,
    const int* __restrict__ flag,
    u16* __restrict__ xsF)
{
    __shared__ __align__(16) u16 As[128 * LDA];
    __shared__ __align__(16) u16 Bs[128 * LDA];
    __shared__ int rowS[128];
    __shared__ int rowM[128];

    int f32 = *flag;
    int tid = threadIdx.x;
    int mBase = blockIdx.y * 128;
    int jGlob = blockIdx.x * 128;    // [0,1024), 128-tile stays in one dir
    int dir = jGlob >> 9;
    int jj = jGlob & 511;
    const void* w_ih = dir ? w_ih_b : w_ih_f;
    const void* b_ih = dir ? b_ih_b : b_ih_f;
    const void* b_hh = dir ? b_hh_b : b_hh_f;

    int b = mBase >> 8;              // one batch per block (128 | 256)
    int posBase = mBase & 255;
    int len = lens[b];

    if (tid < 128) {
        int i = mBase + tid;
        rowS[tid] = sents[i] * 300;
        rowM[tid] = masks[i] * 50;
    }
    int wv = tid >> 6, lane = tid & 63;
    int quad = lane >> 4, col = lane & 15;
    int mS = tid >> 4;               // staging row for this thread
    int k2S = (tid & 15) << 1;       // staging k-pair base
    f32x4 acc[2][8] = {};
    __syncthreads();

    for (int kt = 0; kt < 11; ++kt) {
        int k0 = kt * 32;
        u32 aR[8], bR[8];
        if (f32) {
#pragma unroll
            for (int e = 0; e < 8; ++e) {
                int m = mS + e * 16;
                int gk = k0 + k2S;
                float2 v = make_float2(0.f, 0.f);
                if (gk < 300)
                    v = *(const float2*)((const float*)word_embed + rowS[m] + gk);
                else if (gk < 350)
                    v = *(const float2*)((const float*)mask_embed + rowM[m] + gk - 300);
                aR[e] = pack2(v.x, v.y);
                float2 w2 = make_float2(0.f, 0.f);
                if (gk < 350)
                    w2 = *(const float2*)((const float*)w_ih + (long)(jj + m) * 350 + gk);
                bR[e] = pack2(w2.x, w2.y);
            }
        } else {
#pragma unroll
            for (int e = 0; e < 8; ++e) {
                int m = mS + e * 16;
                int gk = k0 + k2S;
                u32 v = 0;
                if (gk < 300)
                    v = *(const u32*)((const u16*)word_embed + rowS[m] + gk);
                else if (gk < 350)
                    v = *(const u32*)((const u16*)mask_embed + rowM[m] + gk - 300);
                aR[e] = v;
                u32 w2 = 0;
                if (gk < 350)
                    w2 = *(const u32*)((const u16*)w_ih + (long)(jj + m) * 350 + gk);
                bR[e] = w2;
            }
        }
        __syncthreads();   // prior tile's fragment reads complete
#pragma unroll
        for (int e = 0; e < 8; ++e) {
            int m = mS + e * 16;
            *(u32*)&As[m * LDA + k2S] = aR[e];
            *(u32*)&Bs[m * LDA + k2S] = bR[e];
        }
        __syncthreads();
        bf16x8 af[2], bfr[8];
#pragma unroll
        for (int mt = 0; mt < 2; ++mt)
            af[mt] = *(const bf16x8*)&As[(wv * 32 + mt * 16 + col) * LDA + quad * 8];
#pragma unroll
        for (int nt = 0; nt < 8; ++nt)
            bfr[nt] = *(const bf16x8*)&Bs[(nt * 16 + col) * LDA + quad * 8];
#pragma unroll
        for (int mt = 0; mt < 2; ++mt)
#pragma unroll
            for (int nt = 0; nt < 8; ++nt)
                acc[mt][nt] = __builtin_amdgcn_mfma_f32_16x16x32_bf16(
                    af[mt], bfr[nt], acc[mt][nt], 0, 0, 0);
    }

    // epilogue: bias + scatter into R9 xsF fragment layout
    int bgv = b >> 2, quadv = b & 3;
#pragma unroll
    for (int nt = 0; nt < 8; ++nt) {
        int ng = jj + nt * 16 + col;           // gate-dim in [0,512)
        float bias = loadf(b_ih, ng, f32) + loadf(b_hh, ng, f32);
        int g = ng >> 7, dd = ng & 127;
        int wvx = dd >> 4, colv = dd & 15;
        int row = ((dir * 16 + bgv) * 8 + wvx) * 4 + g;
        int lanev = quadv * 16 + colv;
#pragma unroll
        for (int mt = 0; mt < 2; ++mt)
#pragma unroll
            for (int r = 0; r < 4; ++r) {
                int pos = posBase + wv * 32 + mt * 16 + quad * 4 + r;
                int s = dir ? (len - 1 - pos) : pos;
                if (s >= 0) {
                    long idxe = ((long)(row * 32 + (s >> 3))) * 512
                                + lanev * 8 + (s & 7);
                    xsF[idxe] = f2bf(acc[mt][nt][r] + bias);
                }
            }
    }
}

// ---------------------------------------------------------------------------
// Kernel 2: MFMA LSTM v4 (R12-exact, proven 191 us). 32 blocks x 512 thr.
// ---------------------------------------------------------------------------
__global__ __launch_bounds__(512, 1) void lstm_mfma_kernel(
    const u16* __restrict__ xsF,
    const void* __restrict__ w_hh_f, const void* __restrict__ w_hh_b,
    const int* __restrict__ lens, const int* __restrict__ flag,
    u16* __restrict__ context)
{
    int f32 = *flag;
    int blk = blockIdx.x;
    int dir = blk >> 4, bg = blk & 15;
    int tid = threadIdx.x;
    int w = tid >> 6, lane = tid & 63;
    int quad = lane >> 4, col = lane & 15;
    const void* w_hh = dir ? w_hh_b : w_hh_f;

    __shared__ __align__(16) u16 hbuf[2][16 * 128];  // swizzled dbuf, 8 KB
    __shared__ __align__(16) u16 hist[16 * 512];     // [t&15][m*128+d], 16 KB
    __shared__ int len_s[4];
    __shared__ int maxlen_s;

    if (tid < 4) len_s[tid] = lens[bg * 4 + tid];
    for (int i = tid; i < 2 * 16 * 128; i += 512) ((u16*)hbuf)[i] = 0;
    __syncthreads();
    if (tid == 0) {
        int mx = 0;
        for (int m = 0; m < 4; ++m) mx = max(mx, len_s[m]);
        maxlen_s = mx;
    }
    for (int m = 0; m < 4; ++m) {
        int b = bg * 4 + m;
        int len = len_s[m];
        for (int idx = tid; idx < (Lq - len) * HDq; idx += 512) {
            int p = len + (idx >> 7);
            int d = idx & 127;
            context[((b << 8) + p) * Hq + dir * HDq + d] = 0;
        }
    }
    __syncthreads();
    int T16 = (maxlen_s + 15) & ~15;

    bf16x8 wfrag[4][4];
#pragma unroll
    for (int g = 0; g < 4; ++g) {
        int n = g * 128 + w * 16 + col;
#pragma unroll
        for (int c = 0; c < 4; ++c) {
            int k0 = c * 32 + quad * 8;
            bf16x8 fr;
            if (f32) {
                const float* src = (const float*)w_hh + (long)n * 128 + k0;
#pragma unroll
                for (int j = 0; j < 8; ++j) fr[j] = (short)f2bf(src[j]);
            } else {
                fr = *(const bf16x8*)((const u16*)w_hh + (long)n * 128 + k0);
            }
            wfrag[g][c] = fr;
        }
    }

    float c_st = 0.f;
    int mylen = len_s[quad];
    int mloc = quad * 4;
    int dcol = w * 16 + col;
    int rowb = ((dir * 16 + bg) * 8 + w) * 4;

    int nCh = T16 >> 3;
    for (int tc = 0; tc < nCh; ++tc) {
        uint4 xsq[4];
#pragma unroll
        for (int g = 0; g < 4; ++g)
            xsq[g] = *(const uint4*)(xsF + ((long)((rowb + g) * 32 + tc)) * 512
                                     + lane * 8);
#pragma unroll
        for (int u = 0; u < 8; ++u) {
            int t = tc * 8 + u;
            const u16* hb = hbuf[t & 1];
            u16* hn = hbuf[(t + 1) & 1];
            bf16x8 af[4];
#pragma unroll
            for (int c = 0; c < 4; ++c)
                af[c] = *(const bf16x8*)&hb[hswz(col, c * 32 + quad * 8)];
            f32x4 acc[4];
#pragma unroll
            for (int g = 0; g < 4; ++g) {
                f32x4 a4 = {0.f, 0.f, 0.f, 0.f};
                a4[0] = pick8(xsq[g], u);
                acc[g] = a4;
            }
#pragma unroll
            for (int c = 0; c < 4; ++c)
#pragma unroll
                for (int g = 0; g < 4; ++g)
                    acc[g] = __builtin_amdgcn_mfma_f32_16x16x32_bf16(
                        af[c], wfrag[g][c], acc[g], 0, 0, 0);
            bool vld = (t < mylen);
            float i_ = fsigm(acc[0][0]);
            float f_ = fsigm(acc[1][0]);
            float g_ = ftanh(acc[2][0]);
            float o_ = fsigm(acc[3][0]);
            float cn = f_ * c_st + i_ * g_;
            if (vld) c_st = cn;
            u16 hnew = f2bf(o_ * ftanh(cn));
            u16 hv = vld ? hnew : hb[hswz(mloc, dcol)];
            hn[hswz(mloc, dcol)] = hv;
            if (vld) hist[(t & 15) * 512 + quad * 128 + dcol] = hnew;
            __syncthreads();
            if ((t & 15) == 15) {
                int tb = t - 15;
                for (int idx = tid; idx < 4096; idx += 512) {
                    int tl = idx >> 8;
                    int rem = idx & 255;
                    int m = rem >> 6;
                    int d2 = (rem & 63) << 1;
                    int tt = tb + tl;
                    int len = len_s[m];
                    if (tt < len) {
                        int pos = dir ? (len - 1 - tt) : tt;
                        int b = bg * 4 + m;
                        u32 v = *(const u32*)&hist[tl * 512 + m * 128 + d2];
                        *(u32*)&context[((b << 8) + pos) * Hq + dir * HDq + d2] = v;
                    }
                }
                __syncthreads();
            }
        }
    }
}

// ---------------------------------------------------------------------------
// Kernel 3 (R15): tavg partial sums — grid (8 L-chunks x 64 batch).
// atomicAdd into tavgsum[b][h] and msum[b] (zeroed via hipMemsetAsync).
// ---------------------------------------------------------------------------
__global__ void tavg_part_kernel(const int* __restrict__ masks,
                                 const u16* __restrict__ context,
                                 float* __restrict__ tavgsum,
                                 float* __restrict__ msum)
{
    __shared__ int m_s[32];
    int b = blockIdx.y, lc = blockIdx.x;
    int h = threadIdx.x;
    if (h < 32) m_s[h] = masks[(b << 8) + (lc << 5) + h];
    __syncthreads();
    float s = 0.f;
    int mcnt = 0;
    for (int l = 0; l < 32; ++l) {
        int m = m_s[l];
        if (m) {
            s += (float)m * bf2f(context[(((b << 8) + (lc << 5) + l) << 8) + h]);
            mcnt += m;
        }
    }
    atomicAdd(&tavgsum[(b << 8) + h], s);
    if (h == 0 && mcnt) atomicAdd(&msum[b], (float)mcnt);
}

// ---------------------------------------------------------------------------
// Kernel 4 (R15): emit — tavg = tavgsum/msum inline; 4 rows/block.
// Writes TRANSPOSED emit_T[(l*64+b)*2 + {0,1}].
// ---------------------------------------------------------------------------
__global__ void emit_kernel(const u16* __restrict__ context,
                            const float* __restrict__ tavgsum,
                            const float* __restrict__ msum,
                            const void* __restrict__ f2t_w,
                            const void* __restrict__ f2t_b,
                            const int* __restrict__ flag,
                            float* __restrict__ emit_T)
{
    int f32 = *flag;
    int wv = threadIdx.x >> 6;
    int i = (blockIdx.x << 2) + wv;
    int b = i >> 8;
    int l = i & 255;
    int k = threadIdx.x & 63;  // 0..63
    float inv = 1.f / msum[b];
    ushort4 c4 = *(const ushort4*)(context + (long)i * Hq + 4 * k);
    float4 t4 = *(const float4*)(tavgsum + (b << 8) + 4 * k);
    float v0 = bf2f(c4.x) + t4.x * inv, v1 = bf2f(c4.y) + t4.y * inv;
    float v2 = bf2f(c4.z) + t4.z * inv, v3 = bf2f(c4.w) + t4.w * inv;
    int d = 4 * k;
    float p0 = v0 * loadf(f2t_w, d, f32) + v1 * loadf(f2t_w, d + 1, f32) +
               v2 * loadf(f2t_w, d + 2, f32) + v3 * loadf(f2t_w, d + 3, f32);
    float p1 = v0 * loadf(f2t_w, Hq + d, f32) + v1 * loadf(f2t_w, Hq + d + 1, f32) +
               v2 * loadf(f2t_w, Hq + d + 2, f32) + v3 * loadf(f2t_w, Hq + d + 3, f32);
#pragma unroll
    for (int off = 32; off >= 1; off >>= 1) {
        p0 += __shfl_down(p0, off);
        p1 += __shfl_down(p1, off);
    }
    if (k == 0) {
        float2 e = make_float2(p0 + loadf(f2t_b, 0, f32),
                               p1 + loadf(f2t_b, 1, f32));
        *(float2*)(emit_T + ((l << 6) + b) * 2) = e;
    }
}

// ---------------------------------------------------------------------------
// Kernel 5 (R12, proven): CRF forward-backward, transposed [t][b] layouts.
// ---------------------------------------------------------------------------
__global__ void crf_kernel(const float* __restrict__ emit_T,
                           const int* __restrict__ lens,
                           const void* __restrict__ trans,
                           const int* __restrict__ flag,
                           float* __restrict__ alphas_T,
                           float* __restrict__ sp_T,
                           float* __restrict__ spsum)
{
    int f32 = *flag;
    int b = threadIdx.x;
    float t00 = loadf(trans, 0, f32), t01 = loadf(trans, 1, f32);
    float t10 = loadf(trans, 2, f32), t11 = loadf(trans, 3, f32);
    int len = lens[b];

    // ---- forward scan ----
    float a0, a1;
    {
        float2 e0 = *(const float2*)(emit_T + (b << 1));
        a0 = e0.x; a1 = e0.y;
        *(float2*)(alphas_T + (b << 1)) = make_float2(a0, a1);
    }
    for (int tc = 0; tc < 32; ++tc) {
        float2 ebuf[8];
#pragma unroll
        for (int u = 0; u < 8; ++u) {
            int t = tc * 8 + u;
            ebuf[u] = *(const float2*)(emit_T + (((t << 6) + b) << 1));
        }
#pragma unroll
        for (int u = 0; u < 8; ++u) {
            int t = tc * 8 + u;
            if (t >= 1 && t < len) {
                float n0 = ebuf[u].x + lse2f(a0 + t00, a1 + t10);
                float n1 = ebuf[u].y + lse2f(a0 + t01, a1 + t11);
                a0 = n0; a1 = n1;
            }
            if (t >= 1)
                *(float2*)(alphas_T + (((t << 6) + b) << 1)) = make_float2(a0, a1);
        }
    }
    float logZ = lse2f(a0, a1);

    // ---- backward scan ----
    float b0 = 0.f, b1 = 0.f;
    float ssum = 0.f;
    {   // position L-1
        float a255 = alphas_T[((((Lq - 1) << 6) + b) << 1) + 1];
        float v = (Lq - 1 < len) ? __expf(a255 - logZ) : 0.f;
        sp_T[((Lq - 1) << 6) + b] = v; ssum += v;
    }
    for (int tc = 31; tc >= 0; --tc) {
        float2 ebuf[8];
        float abuf[8];   // alpha1 at t-1
#pragma unroll
        for (int u = 0; u < 8; ++u) {
            int t = tc * 8 + u;
            ebuf[u] = *(const float2*)(emit_T + (((t << 6) + b) << 1));
            if (t >= 1)
                abuf[u] = alphas_T[((((t - 1) << 6) + b) << 1) + 1];
        }
#pragma unroll
        for (int uu = 7; uu >= 0; --uu) {
            int t = tc * 8 + uu;
            if (t < 1) break;
            if (t < len) {
                float e0 = ebuf[uu].x, e1 = ebuf[uu].y;
                float n0 = lse2f(t00 + e0 + b0, t01 + e1 + b1);
                float n1 = lse2f(t10 + e0 + b0, t11 + e1 + b1);
                b0 = n0; b1 = n1;
            }
            float v = ((t - 1) < len) ? __expf(abuf[uu] + b1 - logZ) : 0.f;
            sp_T[((t - 1) << 6) + b] = v; ssum += v;
        }
    }
    spsum[b] = ssum;
}

// ---------------------------------------------------------------------------
// Kernel 6 (R15): sentv partial sums — grid (8 L-chunks x 64 batch).
// ---------------------------------------------------------------------------
__global__ void sentv_part_kernel(const float* __restrict__ sp_T,
                                  const u16* __restrict__ context,
                                  float* __restrict__ sentvsum)
{
    __shared__ float sp_s[32];
    int b = blockIdx.y, lc = blockIdx.x;
    int h = threadIdx.x;
    if (h < 32) sp_s[h] = sp_T[(((lc << 5) + h) << 6) + b];
    __syncthreads();
    float s = 0.f;
#pragma unroll 4
    for (int l = 0; l < 32; ++l)
        s += sp_s[l] * bf2f(context[(((b << 8) + (lc << 5) + l) << 8) + h]);
    atomicAdd(&sentvsum[(b << 8) + h], s);
}

// ---------------------------------------------------------------------------
// Kernel 7 (R15): finalize — per-b label-score dots (64 blocks x 256 thr).
// scores[b][j] = sum_h (sentvsum + spsum*tavg)[b,h] * f2l_w[j,h]
// ---------------------------------------------------------------------------
__global__ void finalize_kernel(const float* __restrict__ sentvsum,
                                const float* __restrict__ tavgsum,
                                const float* __restrict__ msum,
                                const float* __restrict__ spsum,
                                const void* __restrict__ f2l_w,
                                const int* __restrict__ flag,
                                float* __restrict__ scores)
{
    __shared__ float red[4][3];
    int f32 = *flag;
    int b = blockIdx.x, h = threadIdx.x;
    float v = sentvsum[(b << 8) + h] +
              spsum[b] * (tavgsum[(b << 8) + h] / msum[b]);
    float p0 = v * loadf(f2l_w, h, f32);
    float p1 = v * loadf(f2l_w, Hq + h, f32);
    float p2 = v * loadf(f2l_w, 2 * Hq + h, f32);
#pragma unroll
    for (int off = 32; off >= 1; off >>= 1) {
        p0 += __shfl_down(p0, off);
        p1 += __shfl_down(p1, off);
        p2 += __shfl_down(p2, off);
    }
    int wv = h >> 6;
    if ((h & 63) == 0) { red[wv][0] = p0; red[wv][1] = p1; red[wv][2] = p2; }
    __syncthreads();
    if (h == 0) {
        scores[b * 4 + 0] = red[0][0] + red[1][0] + red[2][0] + red[3][0];
        scores[b * 4 + 1] = red[0][1] + red[1][1] + red[2][1] + red[3][1];
        scores[b * 4 + 2] = red[0][2] + red[1][2] + red[2][2] + red[3][2];
    }
}

// ---------------------------------------------------------------------------
// Kernel 8 (R15): final2 — logsumexp loss + penalties -> 2 outputs.
// ---------------------------------------------------------------------------
__global__ void final2_kernel(const float* __restrict__ scores,
                              const float* __restrict__ spsum,
                              const void* __restrict__ f2l_b,
                              const void* __restrict__ trans,
                              const int* __restrict__ labels,
                              const int* __restrict__ flag,
                              void* __restrict__ out)
{
    int f32 = *flag;
    int b = threadIdx.x;  // 64 lanes
    float s0 = scores[b * 4 + 0] + loadf(f2l_b, 0, f32);
    float s1 = scores[b * 4 + 1] + loadf(f2l_b, 1, f32);
    float s2 = scores[b * 4 + 2] + loadf(f2l_b, 2, f32);
    float m = fmaxf(s0, fmaxf(s1, s2));
    float lse = m + logf(expf(s0 - m) + expf(s1 - m) + expf(s2 - m));
    int lab = labels[b];
    float sc = lab == 0 ? s0 : (lab == 1 ? s1 : s2);
    float loss = lse - sc;
    float sn = spsum[b];
#pragma unroll
    for (int off = 32; off >= 1; off >>= 1) {
        loss += __shfl_down(loss, off);
        sn += __shfl_down(sn, off);
    }
    if (b == 0) {
        float cls = loss / 64.f;
        float t00 = loadf(trans, 0, f32), t01 = loadf(trans, 1, f32);
        float t10 = loadf(trans, 2, f32), t11 = loadf(trans, 3, f32);
        float pena = fmaxf(t10 - t00, 0.f) + fmaxf(t01 - t11, 0.f);
        float np = 1.0f * pena + 0.1f * (sn / 64.f);
        if (f32) {
            ((float*)out)[0] = cls;
            ((float*)out)[1] = np;
        } else {
            ((__hip_bfloat16*)out)[0] = __float2bfloat16(cls);
            ((__hip_bfloat16*)out)[1] = __float2bfloat16(np);
        }
    }
}

extern "C" void kernel_launch(void* const* d_in, const int* in_sizes, int n_in,
                              void* d_out, int out_size, void* d_ws, size_t ws_size,
                              hipStream_t stream)
{
    const int* sents  = (const int*)d_in[0];
    const int* masks  = (const int*)d_in[1];
    const int* labels = (const int*)d_in[2];
    const int* lens   = (const int*)d_in[3];
    const void* word_embed = d_in[4];
    const void* mask_embed = d_in[5];
    const void* w_ih_f = d_in[6];
    const void* w_hh_f = d_in[7];
    const void* b_ih_f = d_in[8];
    const void* b_hh_f = d_in[9];
    const void* w_ih_b = d_in[10];
    const void* w_hh_b = d_in[11];
    const void* b_ih_b = d_in[12];
    const void* b_hh_b = d_in[13];
    const void* f2t_w  = d_in[14];
    const void* f2t_b  = d_in[15];
    const void* trans  = d_in[16];
    const void* f2l_w  = d_in[17];
    const void* f2l_b  = d_in[18];

    // workspace: identical 42.4 MB budget. After lstm completes, the xsF
    // region (32 MB) is dead — the reduction accumulators live there,
    // zeroed by a stream-ordered memset between lstm and tavg_part.
    char* wsb = (char*)d_ws;
    size_t off = 33554432;                   // xsF: 1024*32*512 bf16 = 32 MB
    u16*   xsF     = (u16*)wsb;
    float* tavgsum  = (float*)wsb;               // [64*256] f32 (in dead xsF)
    float* sentvsum = (float*)(wsb + 65536);     // [64*256] f32
    float* msum     = (float*)(wsb + 131072);    // [64] f32
    float* scores   = (float*)(wsb + 131584);    // [64*4] f32 (fully written)
    u16*   context = (u16*)(wsb + off);      off += 8388608;
    off += 65536;                            // (old tavg slot, unused)
    float* alphas  = (float*)(wsb + off);    off += 131072;
    float* emit    = (float*)(wsb + off);    off += 131072;
    float* sp      = (float*)(wsb + off);    off += 65536;
    float* spsum   = (float*)(wsb + off);    off += 4096;
    off += 65536;                            // (old sentv slot, unused)
    int*   flag    = (int*)(wsb + off);

    detect_kernel<<<1, 64, 0, stream>>>(word_embed, flag);

    gemm_xs_kernel<<<dim3(8, 128), 256, 0, stream>>>(
        sents, masks, lens, word_embed, mask_embed,
        w_ih_f, w_ih_b, b_ih_f, b_hh_f, b_ih_b, b_hh_b, flag, xsF);

    lstm_mfma_kernel<<<32, 512, 0, stream>>>(
        xsF, w_hh_f, w_hh_b, lens, flag, context);

    // zero the accumulators (xsF now dead; stream-ordered after lstm)
    hipMemsetAsync(wsb, 0, 131328, stream);

    tavg_part_kernel<<<dim3(8, 64), 256, 0, stream>>>(
        masks, context, tavgsum, msum);

    emit_kernel<<<Bq * Lq / 4, 256, 0, stream>>>(
        context, tavgsum, msum, f2t_w, f2t_b, flag, emit);

    crf_kernel<<<1, 64, 0, stream>>>(emit, lens, trans, flag, alphas, sp, spsum);

    sentv_part_kernel<<<dim3(8, 64), 256, 0, stream>>>(sp, context, sentvsum);

    finalize_kernel<<<Bq, 256, 0, stream>>>(
        sentvsum, tavgsum, msum, spsum, f2l_w, flag, scores);

    final2_kernel<<<1, 64, 0, stream>>>(
        scores, spsum, f2l_b, trans, labels, flag, d_out);
}

// Round 16
// 489.810 us; speedup vs baseline: 1.8533x; 1.0935x over previous
//
#include <hip/hip_runtime.h>
#include <hip/hip_bf16.h>

#define Bq 64
#define Lq 256
#define Dq 350
#define HDq 128
#define Hq 256
#define G4 512   // 4*HD

typedef unsigned short u16;
typedef unsigned int u32;
typedef __attribute__((ext_vector_type(8))) short bf16x8;
typedef __attribute__((ext_vector_type(4))) float f32x4;

__device__ __forceinline__ float bf2f(u16 u) {
    return __uint_as_float(((u32)u) << 16);
}
__device__ __forceinline__ u16 f2bf(float f) {
    __hip_bfloat16 h = __float2bfloat16(f);
    return *(u16*)&h;
}
__device__ __forceinline__ float bflo(u32 u) {
    return __uint_as_float(u << 16);
}
__device__ __forceinline__ float bfhi(u32 u) {
    return __uint_as_float(u & 0xffff0000u);
}
__device__ __forceinline__ float loadf(const void* p, long i, int f32) {
    return f32 ? ((const float*)p)[i] : bf2f(((const u16*)p)[i]);
}
// extract bf16 element i (0..7) from a uint4 (compile-time i folds to regs)
__device__ __forceinline__ float pick8(uint4 q, int i) {
    u32 w = (i >> 1) == 0 ? q.x : (i >> 1) == 1 ? q.y : (i >> 1) == 2 ? q.z : q.w;
    return (i & 1) ? bfhi(w) : bflo(w);
}
__device__ __forceinline__ float fsigm(float x) {
    return 1.f / (1.f + __expf(-x));
}
__device__ __forceinline__ float ftanh(float x) {
    return 1.f - 2.f / (__expf(2.f * x) + 1.f);
}
__device__ __forceinline__ float lse2f(float x, float y) {
    float m = fmaxf(x, y);
    return m + __logf(__expf(x - m) + __expf(y - m));
}
// swizzled h-buffer index (u16 units)
__device__ __forceinline__ int hswz(int m, int k) {
    return m * 128 + ((((k >> 3) + m) & 15) << 3) + (k & 7);
}
__device__ __forceinline__ u32 pack2(float lo, float hi) {
    return ((u32)f2bf(hi) << 16) | (u32)f2bf(lo);
}

// ---------------------------------------------------------------------------
// Kernel 0: dtype detector (proven R4+). flag=1 => float inputs are f32.
// ---------------------------------------------------------------------------
__global__ void detect_kernel(const void* we, int* flag) {
    if (threadIdx.x == 0 && blockIdx.x == 0) {
        const u16* p = (const u16*)we;
        int big = 0;
        for (int i = 0; i < 256; ++i) {
            float a = fabsf(bf2f(p[i]));
            if (!(a < 2.f)) big++;   // counts NaN too
        }
        *flag = (big > 16) ? 1 : 0;
    }
}

// ---------------------------------------------------------------------------
// Kernel 1 (R16): MFMA gather+GEMM, SOFTWARE-PIPELINED K-loop.
// Tile k+1's staging loads issue before tile k's MFMA (register dbuf);
// the vmcnt wait lands at the next LDS write — HBM latency overlaps compute.
// Addressing identical to proven R11.
// ---------------------------------------------------------------------------
#define LDA 40   // u16 stride per m-row in LDS

__global__ __launch_bounds__(256) void gemm_xs_kernel(
    const int* __restrict__ sents, const int* __restrict__ masks,
    const int* __restrict__ lens,
    const void* __restrict__ word_embed,
    const void* __restrict__ mask_embed,
    const void* __restrict__ w_ih_f, const void* __restrict__ w_ih_b,
    const void* __restrict__ b_ih_f, const void* __restrict__ b_hh_f,
    const void* __restrict__ b_ih_b, const void* __restrict__ b_hh_b,
    const int* __restrict__ flag,
    u16* __restrict__ xsF)
{
    __shared__ __align__(16) u16 As[128 * LDA];
    __shared__ __align__(16) u16 Bs[128 * LDA];
    __shared__ int rowS[128];
    __shared__ int rowM[128];

    int f32 = *flag;
    int tid = threadIdx.x;
    int mBase = blockIdx.y * 128;
    int jGlob = blockIdx.x * 128;    // [0,1024), 128-tile stays in one dir
    int dir = jGlob >> 9;
    int jj = jGlob & 511;
    const void* w_ih = dir ? w_ih_b : w_ih_f;
    const void* b_ih = dir ? b_ih_b : b_ih_f;
    const void* b_hh = dir ? b_hh_b : b_hh_f;

    int b = mBase >> 8;              // one batch per block (128 | 256)
    int posBase = mBase & 255;
    int len = lens[b];

    if (tid < 128) {
        int i = mBase + tid;
        rowS[tid] = sents[i] * 300;
        rowM[tid] = masks[i] * 50;
    }
    int wv = tid >> 6, lane = tid & 63;
    int quad = lane >> 4, col = lane & 15;
    int mS = tid >> 4;               // staging row for this thread
    int k2S = (tid & 15) << 1;       // staging k-pair base
    f32x4 acc[2][8] = {};
    __syncthreads();

    // register double-buffer for staging
    u32 aRA[8], bRA[8], aRB[8], bRB[8];

    // issue tile 0's loads
#define LOAD_TILE(KT, AR, BR)                                                  \
    {                                                                          \
        int k0 = (KT) * 32;                                                    \
        if (f32) {                                                             \
            _Pragma("unroll")                                                  \
            for (int e = 0; e < 8; ++e) {                                      \
                int m = mS + e * 16;                                           \
                int gk = k0 + k2S;                                             \
                float2 v = make_float2(0.f, 0.f);                              \
                if (gk < 300)                                                  \
                    v = *(const float2*)((const float*)word_embed + rowS[m] + gk); \
                else if (gk < 350)                                             \
                    v = *(const float2*)((const float*)mask_embed + rowM[m] + gk - 300); \
                AR[e] = pack2(v.x, v.y);                                       \
                float2 w2 = make_float2(0.f, 0.f);                             \
                if (gk < 350)                                                  \
                    w2 = *(const float2*)((const float*)w_ih + (long)(jj + m) * 350 + gk); \
                BR[e] = pack2(w2.x, w2.y);                                     \
            }                                                                  \
        } else {                                                               \
            _Pragma("unroll")                                                  \
            for (int e = 0; e < 8; ++e) {                                      \
                int m = mS + e * 16;                                           \
                int gk = k0 + k2S;                                             \
                u32 v = 0;                                                     \
                if (gk < 300)                                                  \
                    v = *(const u32*)((const u16*)word_embed + rowS[m] + gk);  \
                else if (gk < 350)                                             \
                    v = *(const u32*)((const u16*)mask_embed + rowM[m] + gk - 300); \
                AR[e] = v;                                                     \
                u32 w2 = 0;                                                    \
                if (gk < 350)                                                  \
                    w2 = *(const u32*)((const u16*)w_ih + (long)(jj + m) * 350 + gk); \
                BR[e] = w2;                                                    \
            }                                                                  \
        }                                                                      \
    }

    LOAD_TILE(0, aRA, bRA);

#pragma unroll
    for (int kt = 0; kt < 11; ++kt) {
        __syncthreads();   // prior tile's fragment reads complete
        // LDS writes from this tile's registers (waits on its loads)
        if (kt & 1) {
#pragma unroll
            for (int e = 0; e < 8; ++e) {
                int m = mS + e * 16;
                *(u32*)&As[m * LDA + k2S] = aRB[e];
                *(u32*)&Bs[m * LDA + k2S] = bRB[e];
            }
        } else {
#pragma unroll
            for (int e = 0; e < 8; ++e) {
                int m = mS + e * 16;
                *(u32*)&As[m * LDA + k2S] = aRA[e];
                *(u32*)&Bs[m * LDA + k2S] = bRA[e];
            }
        }
        __syncthreads();
        // prefetch next tile's loads (wait lands at next iter's LDS write)
        if (kt < 10) {
            if (kt & 1) {
                LOAD_TILE(kt + 1, aRA, bRA);
            } else {
                LOAD_TILE(kt + 1, aRB, bRB);
            }
        }
        // fragment reads + MFMA on this tile
        bf16x8 af[2], bfr[8];
#pragma unroll
        for (int mt = 0; mt < 2; ++mt)
            af[mt] = *(const bf16x8*)&As[(wv * 32 + mt * 16 + col) * LDA + quad * 8];
#pragma unroll
        for (int nt = 0; nt < 8; ++nt)
            bfr[nt] = *(const bf16x8*)&Bs[(nt * 16 + col) * LDA + quad * 8];
#pragma unroll
        for (int mt = 0; mt < 2; ++mt)
#pragma unroll
            for (int nt = 0; nt < 8; ++nt)
                acc[mt][nt] = __builtin_amdgcn_mfma_f32_16x16x32_bf16(
                    af[mt], bfr[nt], acc[mt][nt], 0, 0, 0);
    }
#undef LOAD_TILE

    // epilogue: bias + scatter into R9 xsF fragment layout
    int bgv = b >> 2, quadv = b & 3;
#pragma unroll
    for (int nt = 0; nt < 8; ++nt) {
        int ng = jj + nt * 16 + col;           // gate-dim in [0,512)
        float bias = loadf(b_ih, ng, f32) + loadf(b_hh, ng, f32);
        int g = ng >> 7, dd = ng & 127;
        int wvx = dd >> 4, colv = dd & 15;
        int row = ((dir * 16 + bgv) * 8 + wvx) * 4 + g;
        int lanev = quadv * 16 + colv;
#pragma unroll
        for (int mt = 0; mt < 2; ++mt)
#pragma unroll
            for (int r = 0; r < 4; ++r) {
                int pos = posBase + wv * 32 + mt * 16 + quad * 4 + r;
                int s = dir ? (len - 1 - pos) : pos;
                if (s >= 0) {
                    long idxe = ((long)(row * 32 + (s >> 3))) * 512
                                + lanev * 8 + (s & 7);
                    xsF[idxe] = f2bf(acc[mt][nt][r] + bias);
                }
            }
    }
}

// ---------------------------------------------------------------------------
// Kernel 2: MFMA LSTM v4 (R12-exact, proven 191 us). 32 blocks x 512 thr.
// ---------------------------------------------------------------------------
__global__ __launch_bounds__(512, 1) void lstm_mfma_kernel(
    const u16* __restrict__ xsF,
    const void* __restrict__ w_hh_f, const void* __restrict__ w_hh_b,
    const int* __restrict__ lens, const int* __restrict__ flag,
    u16* __restrict__ context)
{
    int f32 = *flag;
    int blk = blockIdx.x;
    int dir = blk >> 4, bg = blk & 15;
    int tid = threadIdx.x;
    int w = tid >> 6, lane = tid & 63;
    int quad = lane >> 4, col = lane & 15;
    const void* w_hh = dir ? w_hh_b : w_hh_f;

    __shared__ __align__(16) u16 hbuf[2][16 * 128];  // swizzled dbuf, 8 KB
    __shared__ __align__(16) u16 hist[16 * 512];     // [t&15][m*128+d], 16 KB
    __shared__ int len_s[4];
    __shared__ int maxlen_s;

    if (tid < 4) len_s[tid] = lens[bg * 4 + tid];
    for (int i = tid; i < 2 * 16 * 128; i += 512) ((u16*)hbuf)[i] = 0;
    __syncthreads();
    if (tid == 0) {
        int mx = 0;
        for (int m = 0; m < 4; ++m) mx = max(mx, len_s[m]);
        maxlen_s = mx;
    }
    for (int m = 0; m < 4; ++m) {
        int b = bg * 4 + m;
        int len = len_s[m];
        for (int idx = tid; idx < (Lq - len) * HDq; idx += 512) {
            int p = len + (idx >> 7);
            int d = idx & 127;
            context[((b << 8) + p) * Hq + dir * HDq + d] = 0;
        }
    }
    __syncthreads();
    int T16 = (maxlen_s + 15) & ~15;

    bf16x8 wfrag[4][4];
#pragma unroll
    for (int g = 0; g < 4; ++g) {
        int n = g * 128 + w * 16 + col;
#pragma unroll
        for (int c = 0; c < 4; ++c) {
            int k0 = c * 32 + quad * 8;
            bf16x8 fr;
            if (f32) {
                const float* src = (const float*)w_hh + (long)n * 128 + k0;
#pragma unroll
                for (int j = 0; j < 8; ++j) fr[j] = (short)f2bf(src[j]);
            } else {
                fr = *(const bf16x8*)((const u16*)w_hh + (long)n * 128 + k0);
            }
            wfrag[g][c] = fr;
        }
    }

    float c_st = 0.f;
    int mylen = len_s[quad];
    int mloc = quad * 4;
    int dcol = w * 16 + col;
    int rowb = ((dir * 16 + bg) * 8 + w) * 4;

    int nCh = T16 >> 3;
    for (int tc = 0; tc < nCh; ++tc) {
        uint4 xsq[4];
#pragma unroll
        for (int g = 0; g < 4; ++g)
            xsq[g] = *(const uint4*)(xsF + ((long)((rowb + g) * 32 + tc)) * 512
                                     + lane * 8);
#pragma unroll
        for (int u = 0; u < 8; ++u) {
            int t = tc * 8 + u;
            const u16* hb = hbuf[t & 1];
            u16* hn = hbuf[(t + 1) & 1];
            bf16x8 af[4];
#pragma unroll
            for (int c = 0; c < 4; ++c)
                af[c] = *(const bf16x8*)&hb[hswz(col, c * 32 + quad * 8)];
            f32x4 acc[4];
#pragma unroll
            for (int g = 0; g < 4; ++g) {
                f32x4 a4 = {0.f, 0.f, 0.f, 0.f};
                a4[0] = pick8(xsq[g], u);
                acc[g] = a4;
            }
#pragma unroll
            for (int c = 0; c < 4; ++c)
#pragma unroll
                for (int g = 0; g < 4; ++g)
                    acc[g] = __builtin_amdgcn_mfma_f32_16x16x32_bf16(
                        af[c], wfrag[g][c], acc[g], 0, 0, 0);
            bool vld = (t < mylen);
            float i_ = fsigm(acc[0][0]);
            float f_ = fsigm(acc[1][0]);
            float g_ = ftanh(acc[2][0]);
            float o_ = fsigm(acc[3][0]);
            float cn = f_ * c_st + i_ * g_;
            if (vld) c_st = cn;
            u16 hnew = f2bf(o_ * ftanh(cn));
            u16 hv = vld ? hnew : hb[hswz(mloc, dcol)];
            hn[hswz(mloc, dcol)] = hv;
            if (vld) hist[(t & 15) * 512 + quad * 128 + dcol] = hnew;
            __syncthreads();
            if ((t & 15) == 15) {
                int tb = t - 15;
                for (int idx = tid; idx < 4096; idx += 512) {
                    int tl = idx >> 8;
                    int rem = idx & 255;
                    int m = rem >> 6;
                    int d2 = (rem & 63) << 1;
                    int tt = tb + tl;
                    int len = len_s[m];
                    if (tt < len) {
                        int pos = dir ? (len - 1 - tt) : tt;
                        int b = bg * 4 + m;
                        u32 v = *(const u32*)&hist[tl * 512 + m * 128 + d2];
                        *(u32*)&context[((b << 8) + pos) * Hq + dir * HDq + d2] = v;
                    }
                }
                __syncthreads();
            }
        }
    }
}

// ---------------------------------------------------------------------------
// Kernel 3 (R15, proven): tavg partial sums — grid (8 x 64).
// ---------------------------------------------------------------------------
__global__ void tavg_part_kernel(const int* __restrict__ masks,
                                 const u16* __restrict__ context,
                                 float* __restrict__ tavgsum,
                                 float* __restrict__ msum)
{
    __shared__ int m_s[32];
    int b = blockIdx.y, lc = blockIdx.x;
    int h = threadIdx.x;
    if (h < 32) m_s[h] = masks[(b << 8) + (lc << 5) + h];
    __syncthreads();
    float s = 0.f;
    int mcnt = 0;
    for (int l = 0; l < 32; ++l) {
        int m = m_s[l];
        if (m) {
            s += (float)m * bf2f(context[(((b << 8) + (lc << 5) + l) << 8) + h]);
            mcnt += m;
        }
    }
    atomicAdd(&tavgsum[(b << 8) + h], s);
    if (h == 0 && mcnt) atomicAdd(&msum[b], (float)mcnt);
}

// ---------------------------------------------------------------------------
// Kernel 4 (R15, proven): emit — tavg=tavgsum/msum inline; 4 rows/block.
// ---------------------------------------------------------------------------
__global__ void emit_kernel(const u16* __restrict__ context,
                            const float* __restrict__ tavgsum,
                            const float* __restrict__ msum,
                            const void* __restrict__ f2t_w,
                            const void* __restrict__ f2t_b,
                            const int* __restrict__ flag,
                            float* __restrict__ emit_T)
{
    int f32 = *flag;
    int wv = threadIdx.x >> 6;
    int i = (blockIdx.x << 2) + wv;
    int b = i >> 8;
    int l = i & 255;
    int k = threadIdx.x & 63;  // 0..63
    float inv = 1.f / msum[b];
    ushort4 c4 = *(const ushort4*)(context + (long)i * Hq + 4 * k);
    float4 t4 = *(const float4*)(tavgsum + (b << 8) + 4 * k);
    float v0 = bf2f(c4.x) + t4.x * inv, v1 = bf2f(c4.y) + t4.y * inv;
    float v2 = bf2f(c4.z) + t4.z * inv, v3 = bf2f(c4.w) + t4.w * inv;
    int d = 4 * k;
    float p0 = v0 * loadf(f2t_w, d, f32) + v1 * loadf(f2t_w, d + 1, f32) +
               v2 * loadf(f2t_w, d + 2, f32) + v3 * loadf(f2t_w, d + 3, f32);
    float p1 = v0 * loadf(f2t_w, Hq + d, f32) + v1 * loadf(f2t_w, Hq + d + 1, f32) +
               v2 * loadf(f2t_w, Hq + d + 2, f32) + v3 * loadf(f2t_w, Hq + d + 3, f32);
#pragma unroll
    for (int off = 32; off >= 1; off >>= 1) {
        p0 += __shfl_down(p0, off);
        p1 += __shfl_down(p1, off);
    }
    if (k == 0) {
        float2 e = make_float2(p0 + loadf(f2t_b, 0, f32),
                               p1 + loadf(f2t_b, 1, f32));
        *(float2*)(emit_T + ((l << 6) + b) * 2) = e;
    }
}

// ---------------------------------------------------------------------------
// Kernel 5 (R12, proven): CRF forward-backward, transposed [t][b] layouts.
// ---------------------------------------------------------------------------
__global__ void crf_kernel(const float* __restrict__ emit_T,
                           const int* __restrict__ lens,
                           const void* __restrict__ trans,
                           const int* __restrict__ flag,
                           float* __restrict__ alphas_T,
                           float* __restrict__ sp_T,
                           float* __restrict__ spsum)
{
    int f32 = *flag;
    int b = threadIdx.x;
    float t00 = loadf(trans, 0, f32), t01 = loadf(trans, 1, f32);
    float t10 = loadf(trans, 2, f32), t11 = loadf(trans, 3, f32);
    int len = lens[b];

    // ---- forward scan ----
    float a0, a1;
    {
        float2 e0 = *(const float2*)(emit_T + (b << 1));
        a0 = e0.x; a1 = e0.y;
        *(float2*)(alphas_T + (b << 1)) = make_float2(a0, a1);
    }
    for (int tc = 0; tc < 32; ++tc) {
        float2 ebuf[8];
#pragma unroll
        for (int u = 0; u < 8; ++u) {
            int t = tc * 8 + u;
            ebuf[u] = *(const float2*)(emit_T + (((t << 6) + b) << 1));
        }
#pragma unroll
        for (int u = 0; u < 8; ++u) {
            int t = tc * 8 + u;
            if (t >= 1 && t < len) {
                float n0 = ebuf[u].x + lse2f(a0 + t00, a1 + t10);
                float n1 = ebuf[u].y + lse2f(a0 + t01, a1 + t11);
                a0 = n0; a1 = n1;
            }
            if (t >= 1)
                *(float2*)(alphas_T + (((t << 6) + b) << 1)) = make_float2(a0, a1);
        }
    }
    float logZ = lse2f(a0, a1);

    // ---- backward scan ----
    float b0 = 0.f, b1 = 0.f;
    float ssum = 0.f;
    {   // position L-1
        float a255 = alphas_T[((((Lq - 1) << 6) + b) << 1) + 1];
        float v = (Lq - 1 < len) ? __expf(a255 - logZ) : 0.f;
        sp_T[((Lq - 1) << 6) + b] = v; ssum += v;
    }
    for (int tc = 31; tc >= 0; --tc) {
        float2 ebuf[8];
        float abuf[8];   // alpha1 at t-1
#pragma unroll
        for (int u = 0; u < 8; ++u) {
            int t = tc * 8 + u;
            ebuf[u] = *(const float2*)(emit_T + (((t << 6) + b) << 1));
            if (t >= 1)
                abuf[u] = alphas_T[((((t - 1) << 6) + b) << 1) + 1];
        }
#pragma unroll
        for (int uu = 7; uu >= 0; --uu) {
            int t = tc * 8 + uu;
            if (t < 1) break;
            if (t < len) {
                float e0 = ebuf[uu].x, e1 = ebuf[uu].y;
                float n0 = lse2f(t00 + e0 + b0, t01 + e1 + b1);
                float n1 = lse2f(t10 + e0 + b0, t11 + e1 + b1);
                b0 = n0; b1 = n1;
            }
            float v = ((t - 1) < len) ? __expf(abuf[uu] + b1 - logZ) : 0.f;
            sp_T[((t - 1) << 6) + b] = v; ssum += v;
        }
    }
    spsum[b] = ssum;
}

// ---------------------------------------------------------------------------
// Kernel 6 (R15, proven): sentv partial sums — grid (8 x 64).
// ---------------------------------------------------------------------------
__global__ void sentv_part_kernel(const float* __restrict__ sp_T,
                                  const u16* __restrict__ context,
                                  float* __restrict__ sentvsum)
{
    __shared__ float sp_s[32];
    int b = blockIdx.y, lc = blockIdx.x;
    int h = threadIdx.x;
    if (h < 32) sp_s[h] = sp_T[(((lc << 5) + h) << 6) + b];
    __syncthreads();
    float s = 0.f;
#pragma unroll 4
    for (int l = 0; l < 32; ++l)
        s += sp_s[l] * bf2f(context[(((b << 8) + (lc << 5) + l) << 8) + h]);
    atomicAdd(&sentvsum[(b << 8) + h], s);
}

// ---------------------------------------------------------------------------
// Kernel 7 (R15, proven): finalize — per-b label-score dots.
// ---------------------------------------------------------------------------
__global__ void finalize_kernel(const float* __restrict__ sentvsum,
                                const float* __restrict__ tavgsum,
                                const float* __restrict__ msum,
                                const float* __restrict__ spsum,
                                const void* __restrict__ f2l_w,
                                const int* __restrict__ flag,
                                float* __restrict__ scores)
{
    __shared__ float red[4][3];
    int f32 = *flag;
    int b = blockIdx.x, h = threadIdx.x;
    float v = sentvsum[(b << 8) + h] +
              spsum[b] * (tavgsum[(b << 8) + h] / msum[b]);
    float p0 = v * loadf(f2l_w, h, f32);
    float p1 = v * loadf(f2l_w, Hq + h, f32);
    float p2 = v * loadf(f2l_w, 2 * Hq + h, f32);
#pragma unroll
    for (int off = 32; off >= 1; off >>= 1) {
        p0 += __shfl_down(p0, off);
        p1 += __shfl_down(p1, off);
        p2 += __shfl_down(p2, off);
    }
    int wv = h >> 6;
    if ((h & 63) == 0) { red[wv][0] = p0; red[wv][1] = p1; red[wv][2] = p2; }
    __syncthreads();
    if (h == 0) {
        scores[b * 4 + 0] = red[0][0] + red[1][0] + red[2][0] + red[3][0];
        scores[b * 4 + 1] = red[0][1] + red[1][1] + red[2][1] + red[3][1];
        scores[b * 4 + 2] = red[0][2] + red[1][2] + red[2][2] + red[3][2];
    }
}

// ---------------------------------------------------------------------------
// Kernel 8 (R15, proven): final2 — logsumexp loss + penalties -> 2 outputs.
// ---------------------------------------------------------------------------
__global__ void final2_kernel(const float* __restrict__ scores,
                              const float* __restrict__ spsum,
                              const void* __restrict__ f2l_b,
                              const void* __restrict__ trans,
                              const int* __restrict__ labels,
                              const int* __restrict__ flag,
                              void* __restrict__ out)
{
    int f32 = *flag;
    int b = threadIdx.x;  // 64 lanes
    float s0 = scores[b * 4 + 0] + loadf(f2l_b, 0, f32);
    float s1 = scores[b * 4 + 1] + loadf(f2l_b, 1, f32);
    float s2 = scores[b * 4 + 2] + loadf(f2l_b, 2, f32);
    float m = fmaxf(s0, fmaxf(s1, s2));
    float lse = m + logf(expf(s0 - m) + expf(s1 - m) + expf(s2 - m));
    int lab = labels[b];
    float sc = lab == 0 ? s0 : (lab == 1 ? s1 : s2);
    float loss = lse - sc;
    float sn = spsum[b];
#pragma unroll
    for (int off = 32; off >= 1; off >>= 1) {
        loss += __shfl_down(loss, off);
        sn += __shfl_down(sn, off);
    }
    if (b == 0) {
        float cls = loss / 64.f;
        float t00 = loadf(trans, 0, f32), t01 = loadf(trans, 1, f32);
        float t10 = loadf(trans, 2, f32), t11 = loadf(trans, 3, f32);
        float pena = fmaxf(t10 - t00, 0.f) + fmaxf(t01 - t11, 0.f);
        float np = 1.0f * pena + 0.1f * (sn / 64.f);
        if (f32) {
            ((float*)out)[0] = cls;
            ((float*)out)[1] = np;
        } else {
            ((__hip_bfloat16*)out)[0] = __float2bfloat16(cls);
            ((__hip_bfloat16*)out)[1] = __float2bfloat16(np);
        }
    }
}

extern "C" void kernel_launch(void* const* d_in, const int* in_sizes, int n_in,
                              void* d_out, int out_size, void* d_ws, size_t ws_size,
                              hipStream_t stream)
{
    const int* sents  = (const int*)d_in[0];
    const int* masks  = (const int*)d_in[1];
    const int* labels = (const int*)d_in[2];
    const int* lens   = (const int*)d_in[3];
    const void* word_embed = d_in[4];
    const void* mask_embed = d_in[5];
    const void* w_ih_f = d_in[6];
    const void* w_hh_f = d_in[7];
    const void* b_ih_f = d_in[8];
    const void* b_hh_f = d_in[9];
    const void* w_ih_b = d_in[10];
    const void* w_hh_b = d_in[11];
    const void* b_ih_b = d_in[12];
    const void* b_hh_b = d_in[13];
    const void* f2t_w  = d_in[14];
    const void* f2t_b  = d_in[15];
    const void* trans  = d_in[16];
    const void* f2l_w  = d_in[17];
    const void* f2l_b  = d_in[18];

    // workspace: identical 42.4 MB budget (accumulators in dead xsF region)
    char* wsb = (char*)d_ws;
    size_t off = 33554432;                   // xsF: 1024*32*512 bf16 = 32 MB
    u16*   xsF     = (u16*)wsb;
    float* tavgsum  = (float*)wsb;               // [64*256] f32 (in dead xsF)
    float* sentvsum = (float*)(wsb + 65536);     // [64*256] f32
    float* msum     = (float*)(wsb + 131072);    // [64] f32
    float* scores   = (float*)(wsb + 131584);    // [64*4] f32 (fully written)
    u16*   context = (u16*)(wsb + off);      off += 8388608;
    off += 65536;                            // (old tavg slot, unused)
    float* alphas  = (float*)(wsb + off);    off += 131072;
    float* emit    = (float*)(wsb + off);    off += 131072;
    float* sp      = (float*)(wsb + off);    off += 65536;
    float* spsum   = (float*)(wsb + off);    off += 4096;
    off += 65536;                            // (old sentv slot, unused)
    int*   flag    = (int*)(wsb + off);

    detect_kernel<<<1, 64, 0, stream>>>(word_embed, flag);

    gemm_xs_kernel<<<dim3(8, 128), 256, 0, stream>>>(
        sents, masks, lens, word_embed, mask_embed,
        w_ih_f, w_ih_b, b_ih_f, b_hh_f, b_ih_b, b_hh_b, flag, xsF);

    lstm_mfma_kernel<<<32, 512, 0, stream>>>(
        xsF, w_hh_f, w_hh_b, lens, flag, context);

    // zero the accumulators (xsF now dead; stream-ordered after lstm)
    hipMemsetAsync(wsb, 0, 131328, stream);

    tavg_part_kernel<<<dim3(8, 64), 256, 0, stream>>>(
        masks, context, tavgsum, msum);

    emit_kernel<<<Bq * Lq / 4, 256, 0, stream>>>(
        context, tavgsum, msum, f2t_w, f2t_b, flag, emit);

    crf_kernel<<<1, 64, 0, stream>>>(emit, lens, trans, flag, alphas, sp, spsum);

    sentv_part_kernel<<<dim3(8, 64), 256, 0, stream>>>(sp, context, sentvsum);

    finalize_kernel<<<Bq, 256, 0, stream>>>(
        sentvsum, tavgsum, msum, spsum, f2l_w, flag, scores);

    final2_kernel<<<1, 64, 0, stream>>>(
        scores, spsum, f2l_b, trans, labels, flag, d_out);
}